// Round 5
// baseline (644.714 us; speedup 1.0000x reference)
//
#include <hip/hip_runtime.h>
#include <math.h>

#define NN 100000
#define EE 1600000
#define GG 64
#define NCLS 10

#define BSH 9                 // bucket = dst >> 9 (512 nodes per bucket)
#define NB 196                // ceil(NN / 512)
#define EPB 4096              // edges per block in bscatter
#define CAP 10240             // bsort LDS staging capacity (ints)

// ---------------- CSR build: two-level counting sort ----------------

__global__ __launch_bounds__(256) void bhist_kernel(const int* __restrict__ dst,
                                                    int* __restrict__ bcnt, int n) {
    __shared__ int h[256];
    int tid = threadIdx.x;
    h[tid] = 0;
    __syncthreads();
    int e0 = blockIdx.x * EPB;
    int e1 = min(e0 + EPB, n);
    for (int e = e0 + tid; e < e1; e += 256) atomicAdd(&h[dst[e] >> BSH], 1);
    __syncthreads();
    if (h[tid]) atomicAdd(&bcnt[tid], h[tid]);
}

__global__ void bscan_kernel(const int* __restrict__ bcnt, int* __restrict__ bbase) {
    __shared__ int s[256];
    int tid = threadIdx.x;
    int v = bcnt[tid];
    s[tid] = v;
    __syncthreads();
    for (int off = 1; off < 256; off <<= 1) {
        int t = (tid >= off) ? s[tid - off] : 0;
        __syncthreads();
        s[tid] += t;
        __syncthreads();
    }
    bbase[tid + 1] = s[tid];
    if (tid == 0) bbase[0] = 0;
}

__global__ __launch_bounds__(256) void bscatter_kernel(
    const int* __restrict__ src, const int* __restrict__ dst,
    int* __restrict__ bfill, const int* __restrict__ bbase,
    int* __restrict__ bsrc, int* __restrict__ bdst, int n) {
    __shared__ int hist[256], lbase[256], goff[256], cnt2[256], sc[256];
    __shared__ int ls[EPB], ld2[EPB];
    __shared__ unsigned char bkt[EPB];
    int tid = threadIdx.x;
    int e0 = blockIdx.x * EPB;
    int e1 = min(e0 + EPB, n);

    hist[tid] = 0;
    cnt2[tid] = 0;
    __syncthreads();
    for (int e = e0 + tid; e < e1; e += 256) atomicAdd(&hist[dst[e] >> BSH], 1);
    __syncthreads();
    sc[tid] = hist[tid];
    __syncthreads();
    for (int off = 1; off < 256; off <<= 1) {
        int t = (tid >= off) ? sc[tid - off] : 0;
        __syncthreads();
        sc[tid] += t;
        __syncthreads();
    }
    lbase[tid] = sc[tid] - hist[tid];
    goff[tid] = hist[tid] > 0 ? atomicAdd(&bfill[tid], hist[tid]) : 0;
    __syncthreads();
    for (int e = e0 + tid; e < e1; e += 256) {
        int s = src[e], d = dst[e];
        int b = d >> BSH;
        int r = atomicAdd(&cnt2[b], 1);
        int slot = lbase[b] + r;
        ls[slot] = s;
        ld2[slot] = d;
        bkt[slot] = (unsigned char)b;
    }
    __syncthreads();
    int m = e1 - e0;
    for (int i = tid; i < m; i += 256) {
        int b = bkt[i];
        int g = bbase[b] + goff[b] + (i - lbase[b]);
        bsrc[g] = ls[i];
        bdst[g] = ld2[i];
    }
}

__global__ __launch_bounds__(512) void bsort_kernel(
    const int* __restrict__ bsrc, const int* __restrict__ bdst,
    const int* __restrict__ bbase, int* __restrict__ rowptr, int* __restrict__ col) {
    __shared__ int cnt[512], cnt2[512], sc[512];
    __shared__ int stage[CAP];
    int b = blockIdx.x;
    int tid = threadIdx.x;
    int ebeg = bbase[b], eend = bbase[b + 1];
    int n0 = b << BSH;
    int nn = min(512, NN - n0);

    cnt[tid] = 0;
    cnt2[tid] = 0;
    __syncthreads();
    for (int e = ebeg + tid; e < eend; e += 512) atomicAdd(&cnt[bdst[e] - n0], 1);
    __syncthreads();
    sc[tid] = cnt[tid];
    __syncthreads();
    for (int off = 1; off < 512; off <<= 1) {
        int t = (tid >= off) ? sc[tid - off] : 0;
        __syncthreads();
        sc[tid] += t;
        __syncthreads();
    }
    int excl = sc[tid] - cnt[tid];
    sc[tid] = excl;
    if (tid < nn) rowptr[n0 + tid] = ebeg + excl;
    if (b == NB - 1 && tid == 0) rowptr[NN] = eend;
    __syncthreads();
    int sz = eend - ebeg;
    bool fits = sz <= CAP;
    for (int e = ebeg + tid; e < eend; e += 512) {
        int d = bdst[e] - n0;
        int r = atomicAdd(&cnt2[d], 1);
        int p = sc[d] + r;
        if (fits) stage[p] = bsrc[e];
        else col[ebeg + p] = bsrc[e];
    }
    __syncthreads();
    if (fits)
        for (int i = tid; i < sz; i += 512) col[ebeg + i] = stage[i];
}

// ---------------- GEMM h = X @ W (+ attention logits) ----------------
// W held in VGPRs (lane l = output col l, Wreg[k] = W[k][l]). X tile (64 rows)
// staged in LDS via coalesced float4; waves read x via uniform-address
// ds_read_b128 (LDS broadcast). 2 rows per pass = 2 independent FMA chains.

template <int K>
__global__ __launch_bounds__(256) void gemm_al_kernel(
    const float* __restrict__ X, const float* __restrict__ W,
    const float* __restrict__ a_src, const float* __restrict__ a_dst,
    float* __restrict__ H, float* __restrict__ ALs, float* __restrict__ ALd, int nrows) {
    __shared__ float Xs[64 * K];
    int tid = threadIdx.x;
    int wave = tid >> 6, lane = tid & 63;
    int r0 = blockIdx.x * 64;

    // stage X tile (guard tail at full-row granularity)
    {
        const float4* Xg = (const float4*)(X + (size_t)r0 * K);
        float4* Xs4 = (float4*)Xs;
        const int nq = 64 * K / 4;
        int valid_q = nrows > r0 ? (min(64, nrows - r0) * K) / 4 : 0;
#pragma unroll
        for (int i = tid; i < nq; i += 256)
            Xs4[i] = (i < valid_q) ? Xg[i] : make_float4(0.f, 0.f, 0.f, 0.f);
    }
    __syncthreads();

    // W into registers AFTER the staging (keeps peak VGPR down)
    float Wreg[K];
#pragma unroll
    for (int k = 0; k < K; ++k) Wreg[k] = W[k * 64 + lane];

    int hh = lane >> 3, cc = lane & 7;
    float as = a_src[hh * 8 + cc];
    float ad = a_dst[hh * 8 + cc];

    for (int rp = 0; rp < 8; ++rp) {
        int ra = wave * 16 + rp * 2;
        const float* xa = &Xs[ra * K];
        const float* xb = xa + K;
        float acc0 = 0.f, acc1 = 0.f;
#pragma unroll
        for (int k = 0; k < K; k += 4) {
            float4 va = *(const float4*)(xa + k);
            float4 vb = *(const float4*)(xb + k);
            acc0 = fmaf(va.x, Wreg[k], acc0);
            acc1 = fmaf(vb.x, Wreg[k], acc1);
            acc0 = fmaf(va.y, Wreg[k + 1], acc0);
            acc1 = fmaf(vb.y, Wreg[k + 1], acc1);
            acc0 = fmaf(va.z, Wreg[k + 2], acc0);
            acc1 = fmaf(vb.z, Wreg[k + 2], acc1);
            acc0 = fmaf(va.w, Wreg[k + 3], acc0);
            acc1 = fmaf(vb.w, Wreg[k + 3], acc1);
        }
        float accs[2] = {acc0, acc1};
#pragma unroll
        for (int j = 0; j < 2; ++j) {
            int r = r0 + ra + j;
            if (r < nrows) {
                H[(size_t)r * 64 + lane] = accs[j];
                float ps = accs[j] * as;
                float pd = accs[j] * ad;
#pragma unroll
                for (int off = 1; off < 8; off <<= 1) {
                    ps += __shfl_xor(ps, off);
                    pd += __shfl_xor(pd, off);
                }
                if (cc == 0) {
                    ALs[r * 8 + hh] = ps;
                    ALd[r * 8 + hh] = pd;
                }
            }
        }
    }
}

// ---------------- GAT aggregation: one wave per dst node, float4 gathers ----------------
// Quarter q (16 lanes) consumes edges j = 4k+q; lane ql holds features 4ql..4ql+3.
// Main path is unpredicated (all j < 4*steps <= m, m wave-uniform), unrolled x8
// for 16 loads in flight. <=3-edge predicated tail per 64-chunk.

__global__ __launch_bounds__(256) void agg_kernel(
    const float* __restrict__ H, const float* __restrict__ ALs, const float* __restrict__ ALd,
    const int* __restrict__ rowptr, const int* __restrict__ col,
    const float* __restrict__ bias, float* __restrict__ Out, int n) {
    int wave = threadIdx.x >> 6, lane = threadIdx.x & 63;
    int d = blockIdx.x * 4 + wave;
    if (d >= n) return;
    int q = lane >> 4, ql = lane & 15;
    int hh = ql >> 1;
    const float4* __restrict__ H4 = (const float4*)H;

    float ad = ALd[d * 8 + hh];
    float4 acc = make_float4(0.f, 0.f, 0.f, 0.f);
    float wsum = 0.f;
    if (q == 0) {  // self loop counted once
        float e = ALs[d * 8 + hh] + ad;
        e = e > 0.f ? e : 0.2f * e;
        float w = __expf(e);
        float4 hv = H4[d * 16 + ql];
        acc.x = w * hv.x; acc.y = w * hv.y; acc.z = w * hv.z; acc.w = w * hv.w;
        wsum = w;
    }

    int beg = rowptr[d], end = rowptr[d + 1];
    for (int base = beg; base < end; base += 64) {
        int m = end - base;
        if (m > 64) m = 64;
        int c = (base + lane < end) ? col[base + lane] : 0;
        int steps = m >> 2;   // all quarters fully valid for k < steps
        int k = 0;
        for (; k + 8 <= steps; k += 8) {
            int j0 = 4 * k + q;
            int s0 = __shfl(c, j0),      s1 = __shfl(c, j0 + 4);
            int s2 = __shfl(c, j0 + 8),  s3 = __shfl(c, j0 + 12);
            int s4 = __shfl(c, j0 + 16), s5 = __shfl(c, j0 + 20);
            int s6 = __shfl(c, j0 + 24), s7 = __shfl(c, j0 + 28);
            float4 h0 = H4[s0 * 16 + ql]; float a0 = ALs[s0 * 8 + hh];
            float4 h1 = H4[s1 * 16 + ql]; float a1 = ALs[s1 * 8 + hh];
            float4 h2 = H4[s2 * 16 + ql]; float a2 = ALs[s2 * 8 + hh];
            float4 h3 = H4[s3 * 16 + ql]; float a3 = ALs[s3 * 8 + hh];
            float4 h4 = H4[s4 * 16 + ql]; float a4 = ALs[s4 * 8 + hh];
            float4 h5 = H4[s5 * 16 + ql]; float a5 = ALs[s5 * 8 + hh];
            float4 h6 = H4[s6 * 16 + ql]; float a6 = ALs[s6 * 8 + hh];
            float4 h7 = H4[s7 * 16 + ql]; float a7 = ALs[s7 * 8 + hh];
            float e0 = a0 + ad; e0 = e0 > 0.f ? e0 : 0.2f * e0; float w0 = __expf(e0);
            float e1 = a1 + ad; e1 = e1 > 0.f ? e1 : 0.2f * e1; float w1 = __expf(e1);
            float e2 = a2 + ad; e2 = e2 > 0.f ? e2 : 0.2f * e2; float w2 = __expf(e2);
            float e3 = a3 + ad; e3 = e3 > 0.f ? e3 : 0.2f * e3; float w3 = __expf(e3);
            float e4 = a4 + ad; e4 = e4 > 0.f ? e4 : 0.2f * e4; float w4 = __expf(e4);
            float e5 = a5 + ad; e5 = e5 > 0.f ? e5 : 0.2f * e5; float w5 = __expf(e5);
            float e6 = a6 + ad; e6 = e6 > 0.f ? e6 : 0.2f * e6; float w6 = __expf(e6);
            float e7 = a7 + ad; e7 = e7 > 0.f ? e7 : 0.2f * e7; float w7 = __expf(e7);
            acc.x = fmaf(w0, h0.x, acc.x); acc.y = fmaf(w0, h0.y, acc.y);
            acc.z = fmaf(w0, h0.z, acc.z); acc.w = fmaf(w0, h0.w, acc.w); wsum += w0;
            acc.x = fmaf(w1, h1.x, acc.x); acc.y = fmaf(w1, h1.y, acc.y);
            acc.z = fmaf(w1, h1.z, acc.z); acc.w = fmaf(w1, h1.w, acc.w); wsum += w1;
            acc.x = fmaf(w2, h2.x, acc.x); acc.y = fmaf(w2, h2.y, acc.y);
            acc.z = fmaf(w2, h2.z, acc.z); acc.w = fmaf(w2, h2.w, acc.w); wsum += w2;
            acc.x = fmaf(w3, h3.x, acc.x); acc.y = fmaf(w3, h3.y, acc.y);
            acc.z = fmaf(w3, h3.z, acc.z); acc.w = fmaf(w3, h3.w, acc.w); wsum += w3;
            acc.x = fmaf(w4, h4.x, acc.x); acc.y = fmaf(w4, h4.y, acc.y);
            acc.z = fmaf(w4, h4.z, acc.z); acc.w = fmaf(w4, h4.w, acc.w); wsum += w4;
            acc.x = fmaf(w5, h5.x, acc.x); acc.y = fmaf(w5, h5.y, acc.y);
            acc.z = fmaf(w5, h5.z, acc.z); acc.w = fmaf(w5, h5.w, acc.w); wsum += w5;
            acc.x = fmaf(w6, h6.x, acc.x); acc.y = fmaf(w6, h6.y, acc.y);
            acc.z = fmaf(w6, h6.z, acc.z); acc.w = fmaf(w6, h6.w, acc.w); wsum += w6;
            acc.x = fmaf(w7, h7.x, acc.x); acc.y = fmaf(w7, h7.y, acc.y);
            acc.z = fmaf(w7, h7.z, acc.z); acc.w = fmaf(w7, h7.w, acc.w); wsum += w7;
        }
        for (; k < steps; ++k) {
            int s = __shfl(c, 4 * k + q);
            float4 hv = H4[s * 16 + ql];
            float a = ALs[s * 8 + hh];
            float e = a + ad; e = e > 0.f ? e : 0.2f * e;
            float w = __expf(e);
            acc.x = fmaf(w, hv.x, acc.x); acc.y = fmaf(w, hv.y, acc.y);
            acc.z = fmaf(w, hv.z, acc.z); acc.w = fmaf(w, hv.w, acc.w);
            wsum += w;
        }
        int t0 = steps << 2;
        if (t0 < m) {  // wave-uniform: <=3 remaining edges
            int j = t0 + q;
            int s = __shfl(c, min(j, m - 1));
            float4 hv = H4[s * 16 + ql];
            float a = ALs[s * 8 + hh];
            float e = a + ad; e = e > 0.f ? e : 0.2f * e;
            float w = j < m ? __expf(e) : 0.f;
            acc.x = fmaf(w, hv.x, acc.x); acc.y = fmaf(w, hv.y, acc.y);
            acc.z = fmaf(w, hv.z, acc.z); acc.w = fmaf(w, hv.w, acc.w);
            wsum += w;
        }
    }

#pragma unroll
    for (int off = 16; off <= 32; off <<= 1) {
        acc.x += __shfl_xor(acc.x, off);
        acc.y += __shfl_xor(acc.y, off);
        acc.z += __shfl_xor(acc.z, off);
        acc.w += __shfl_xor(acc.w, off);
        wsum += __shfl_xor(wsum, off);
    }

    if (q == 0) {
        float inv = 1.f / wsum;
        float4 bv = ((const float4*)bias)[ql];
        float4 o;
        o.x = acc.x * inv + bv.x; o.x = o.x > 0.f ? o.x : expm1f(o.x);
        o.y = acc.y * inv + bv.y; o.y = o.y > 0.f ? o.y : expm1f(o.y);
        o.z = acc.z * inv + bv.z; o.z = o.z > 0.f ? o.z : expm1f(o.z);
        o.w = acc.w * inv + bv.w; o.w = o.w > 0.f ? o.w : expm1f(o.w);
        ((float4*)Out)[d * 16 + ql] = o;
    }
}

// ---------------- global mean pool (batch is sorted) ----------------

__global__ void pool_kernel(const float* __restrict__ H, const int* __restrict__ batch,
                            float* __restrict__ sums, float* __restrict__ cnt, int n) {
    int gw = (int)((blockIdx.x * blockDim.x + threadIdx.x) >> 6);
    int lane = threadIdx.x & 63;
    int n0 = gw * 64;
    if (n0 >= n) return;
    int n1 = min(n0 + 64, n);
    int curb = batch[n0];
    float local = 0.f, c_local = 0.f;
    for (int i = n0; i < n1; ++i) {
        int b = batch[i];
        if (b != curb) {
            atomicAdd(&sums[curb * 64 + lane], local);
            if (lane == 0) atomicAdd(&cnt[curb], c_local);
            local = 0.f;
            c_local = 0.f;
            curb = b;
        }
        local += H[(size_t)i * 64 + lane];
        c_local += 1.f;
    }
    atomicAdd(&sums[curb * 64 + lane], local);
    if (lane == 0) atomicAdd(&cnt[curb], c_local);
}

__global__ void final_kernel(const float* __restrict__ sums, const float* __restrict__ cnt,
                             const float* __restrict__ W, const float* __restrict__ b,
                             float* __restrict__ out) {
    int t = blockIdx.x * blockDim.x + threadIdx.x;
    if (t >= GG * NCLS) return;
    int g = t / NCLS, k = t % NCLS;
    float c = cnt[g];
    if (c < 1.f) c = 1.f;
    float inv = 1.f / c;
    float acc = b[k];
#pragma unroll
    for (int cc = 0; cc < 64; ++cc)
        acc = fmaf(sums[g * 64 + cc] * inv, W[cc * NCLS + k], acc);
    out[t] = acc;
}

// ---------------- launch ----------------

extern "C" void kernel_launch(void* const* d_in, const int* in_sizes, int n_in,
                              void* d_out, int out_size, void* d_ws, size_t ws_size,
                              hipStream_t stream) {
    const float* x    = (const float*)d_in[0];
    const int*   ei   = (const int*)d_in[1];   // [2,E]: src = ei, dst = ei+EE
    const int*   batch = (const int*)d_in[2];
    const float* W1 = (const float*)d_in[3];
    const float* a1s = (const float*)d_in[4];
    const float* a1d = (const float*)d_in[5];
    const float* b1 = (const float*)d_in[6];
    const float* W2 = (const float*)d_in[7];
    const float* a2s = (const float*)d_in[8];
    const float* a2d = (const float*)d_in[9];
    const float* b2 = (const float*)d_in[10];
    const float* W3 = (const float*)d_in[11];
    const float* a3s = (const float*)d_in[12];
    const float* a3d = (const float*)d_in[13];
    const float* b3 = (const float*)d_in[14];
    const float* linW = (const float*)d_in[15];
    const float* linb = (const float*)d_in[16];
    float* out = (float*)d_out;

    char* ws = (char*)d_ws;
    size_t off = 0;
    auto alloc = [&](size_t bytes) -> void* {
        void* p = ws + off;
        off = (off + bytes + 255) & ~(size_t)255;
        return p;
    };
    float* hA     = (float*)alloc((size_t)NN * 64 * 4);
    float* hB     = (float*)alloc((size_t)NN * 64 * 4);
    float* ALs    = (float*)alloc((size_t)NN * 8 * 4);
    float* ALd    = (float*)alloc((size_t)NN * 8 * 4);
    int*   rowptr = (int*)alloc((size_t)(NN + 1) * 4);
    int*   bcnt   = (int*)alloc(256 * 4);
    int*   bfill  = (int*)alloc(256 * 4);
    int*   bbase  = (int*)alloc(257 * 4);
    int*   bsrc   = (int*)alloc((size_t)EE * 4);
    int*   bdst   = (int*)alloc((size_t)EE * 4);
    int*   col    = (int*)alloc((size_t)EE * 4);
    float* sums   = (float*)alloc((size_t)(GG * 64 + GG) * 4);
    float* gcnt   = sums + GG * 64;

    const int NBLK = (NN + 255) / 256;
    const int EB4 = (EE + EPB - 1) / EPB;

    hipMemsetAsync(bcnt, 0, 256 * 4, stream);
    hipMemsetAsync(bfill, 0, 256 * 4, stream);
    bhist_kernel<<<EB4, 256, 0, stream>>>(ei + EE, bcnt, EE);
    bscan_kernel<<<1, 256, 0, stream>>>(bcnt, bbase);
    bscatter_kernel<<<EB4, 256, 0, stream>>>(ei, ei + EE, bfill, bbase, bsrc, bdst, EE);
    bsort_kernel<<<NB, 512, 0, stream>>>(bsrc, bdst, bbase, rowptr, col);

    const int GB = (NN + 63) / 64;   // 1563 blocks, 64 rows each
    const int AB = (NN + 3) / 4;

    gemm_al_kernel<128><<<GB, 256, 0, stream>>>(x, W1, a1s, a1d, hA, ALs, ALd, NN);
    agg_kernel<<<AB, 256, 0, stream>>>(hA, ALs, ALd, rowptr, col, b1, hB, NN);

    gemm_al_kernel<64><<<GB, 256, 0, stream>>>(hB, W2, a2s, a2d, hA, ALs, ALd, NN);
    agg_kernel<<<AB, 256, 0, stream>>>(hA, ALs, ALd, rowptr, col, b2, hB, NN);

    gemm_al_kernel<64><<<GB, 256, 0, stream>>>(hB, W3, a3s, a3d, hA, ALs, ALd, NN);
    agg_kernel<<<AB, 256, 0, stream>>>(hA, ALs, ALd, rowptr, col, b3, hB, NN);

    hipMemsetAsync(sums, 0, (size_t)(GG * 64 + GG) * 4, stream);
    pool_kernel<<<NBLK, 256, 0, stream>>>(hB, batch, sums, gcnt, NN);
    final_kernel<<<3, 256, 0, stream>>>(sums, gcnt, linW, linb, out);
}

// Round 6
// 530.139 us; speedup vs baseline: 1.2161x; 1.2161x over previous
//
#include <hip/hip_runtime.h>
#include <math.h>

#define NN 100000
#define EE 1600000
#define GG 64
#define NCLS 10

#define BSH 9                 // bucket = dst >> 9 (512 nodes per bucket)
#define NB 196                // ceil(NN / 512)
#define EPB 4096              // edges per block in bscatter
#define CAP 10240             // bsort LDS staging capacity (ints)

// ---------------- CSR build: two-level counting sort ----------------

__global__ __launch_bounds__(256) void bhist_kernel(const int* __restrict__ dst,
                                                    int* __restrict__ bcnt, int n) {
    __shared__ int h[256];
    int tid = threadIdx.x;
    h[tid] = 0;
    __syncthreads();
    int e0 = blockIdx.x * EPB;
    int e1 = min(e0 + EPB, n);
    for (int e = e0 + tid; e < e1; e += 256) atomicAdd(&h[dst[e] >> BSH], 1);
    __syncthreads();
    if (h[tid]) atomicAdd(&bcnt[tid], h[tid]);
}

__global__ void bscan_kernel(const int* __restrict__ bcnt, int* __restrict__ bbase) {
    __shared__ int s[256];
    int tid = threadIdx.x;
    int v = bcnt[tid];
    s[tid] = v;
    __syncthreads();
    for (int off = 1; off < 256; off <<= 1) {
        int t = (tid >= off) ? s[tid - off] : 0;
        __syncthreads();
        s[tid] += t;
        __syncthreads();
    }
    bbase[tid + 1] = s[tid];
    if (tid == 0) bbase[0] = 0;
}

__global__ __launch_bounds__(256) void bscatter_kernel(
    const int* __restrict__ src, const int* __restrict__ dst,
    int* __restrict__ bfill, const int* __restrict__ bbase,
    int* __restrict__ bsrc, int* __restrict__ bdst, int n) {
    __shared__ int hist[256], lbase[256], goff[256], cnt2[256], sc[256];
    __shared__ int ls[EPB], ld2[EPB];
    __shared__ unsigned char bkt[EPB];
    int tid = threadIdx.x;
    int e0 = blockIdx.x * EPB;
    int e1 = min(e0 + EPB, n);

    hist[tid] = 0;
    cnt2[tid] = 0;
    __syncthreads();
    for (int e = e0 + tid; e < e1; e += 256) atomicAdd(&hist[dst[e] >> BSH], 1);
    __syncthreads();
    sc[tid] = hist[tid];
    __syncthreads();
    for (int off = 1; off < 256; off <<= 1) {
        int t = (tid >= off) ? sc[tid - off] : 0;
        __syncthreads();
        sc[tid] += t;
        __syncthreads();
    }
    lbase[tid] = sc[tid] - hist[tid];
    goff[tid] = hist[tid] > 0 ? atomicAdd(&bfill[tid], hist[tid]) : 0;
    __syncthreads();
    for (int e = e0 + tid; e < e1; e += 256) {
        int s = src[e], d = dst[e];
        int b = d >> BSH;
        int r = atomicAdd(&cnt2[b], 1);
        int slot = lbase[b] + r;
        ls[slot] = s;
        ld2[slot] = d;
        bkt[slot] = (unsigned char)b;
    }
    __syncthreads();
    int m = e1 - e0;
    for (int i = tid; i < m; i += 256) {
        int b = bkt[i];
        int g = bbase[b] + goff[b] + (i - lbase[b]);
        bsrc[g] = ls[i];
        bdst[g] = ld2[i];
    }
}

__global__ __launch_bounds__(512) void bsort_kernel(
    const int* __restrict__ bsrc, const int* __restrict__ bdst,
    const int* __restrict__ bbase, int* __restrict__ rowptr, int* __restrict__ col) {
    __shared__ int cnt[512], cnt2[512], sc[512];
    __shared__ int stage[CAP];
    int b = blockIdx.x;
    int tid = threadIdx.x;
    int ebeg = bbase[b], eend = bbase[b + 1];
    int n0 = b << BSH;
    int nn = min(512, NN - n0);

    cnt[tid] = 0;
    cnt2[tid] = 0;
    __syncthreads();
    for (int e = ebeg + tid; e < eend; e += 512) atomicAdd(&cnt[bdst[e] - n0], 1);
    __syncthreads();
    sc[tid] = cnt[tid];
    __syncthreads();
    for (int off = 1; off < 512; off <<= 1) {
        int t = (tid >= off) ? sc[tid - off] : 0;
        __syncthreads();
        sc[tid] += t;
        __syncthreads();
    }
    int excl = sc[tid] - cnt[tid];
    sc[tid] = excl;
    if (tid < nn) rowptr[n0 + tid] = ebeg + excl;
    if (b == NB - 1 && tid == 0) rowptr[NN] = eend;
    __syncthreads();
    int sz = eend - ebeg;
    bool fits = sz <= CAP;
    for (int e = ebeg + tid; e < eend; e += 512) {
        int d = bdst[e] - n0;
        int r = atomicAdd(&cnt2[d], 1);
        int p = sc[d] + r;
        if (fits) stage[p] = bsrc[e];
        else col[ebeg + p] = bsrc[e];
    }
    __syncthreads();
    if (fits)
        for (int i = tid; i < sz; i += 512) col[ebeg + i] = stage[i];
}

// ---------------- GEMM h = X @ W (+ attention logits) ----------------
// Register-tiled: block = 64 rows x 64 cols, thread (rg=t>>4, cg=t&15) owns a
// 4x4 tile (16 indep FMA chains). Xs + Ws in LDS; all ds_read_b128 broadcast
// or 2-way (free). VALU-bound: per 4-k chunk, 8 b128 reads vs 64 FMAs.

template <int K>
__global__ __launch_bounds__(256) void gemm_al_kernel(
    const float* __restrict__ X, const float* __restrict__ W,
    const float* __restrict__ a_src, const float* __restrict__ a_dst,
    float* __restrict__ H, float* __restrict__ ALs, float* __restrict__ ALd, int nrows) {
    __shared__ float Xs[64 * K];
    __shared__ float Ws[K * 64];
    int tid = threadIdx.x;
    int r0 = blockIdx.x * 64;

    {   // stage W (K*64 floats, coalesced float4)
        const float4* Wg = (const float4*)W;
        float4* Ws4 = (float4*)Ws;
        for (int i = tid; i < K * 16; i += 256) Ws4[i] = Wg[i];
    }
    {   // stage X tile (row-granular zero-fill at the tail)
        const float4* Xg = (const float4*)(X + (size_t)r0 * K);
        float4* Xs4 = (float4*)Xs;
        const int nq = 64 * K / 4;
        int valid_q = (min(64, nrows - r0) * K) / 4;
        for (int i = tid; i < nq; i += 256)
            Xs4[i] = (i < valid_q) ? Xg[i] : make_float4(0.f, 0.f, 0.f, 0.f);
    }
    __syncthreads();

    int cg = tid & 15, rg = tid >> 4;
    int rbase = rg * 4;
    float4 acc0 = make_float4(0.f, 0.f, 0.f, 0.f);
    float4 acc1 = acc0, acc2 = acc0, acc3 = acc0;

#pragma unroll 2
    for (int k = 0; k < K; k += 4) {
        float4 x0 = *(const float4*)&Xs[(rbase + 0) * K + k];
        float4 x1 = *(const float4*)&Xs[(rbase + 1) * K + k];
        float4 x2 = *(const float4*)&Xs[(rbase + 2) * K + k];
        float4 x3 = *(const float4*)&Xs[(rbase + 3) * K + k];
        float4 w0 = *(const float4*)&Ws[(k + 0) * 64 + 4 * cg];
        float4 w1 = *(const float4*)&Ws[(k + 1) * 64 + 4 * cg];
        float4 w2 = *(const float4*)&Ws[(k + 2) * 64 + 4 * cg];
        float4 w3 = *(const float4*)&Ws[(k + 3) * 64 + 4 * cg];
#define FMA4(A, S, WV) \
        A.x = fmaf(S, WV.x, A.x); A.y = fmaf(S, WV.y, A.y); \
        A.z = fmaf(S, WV.z, A.z); A.w = fmaf(S, WV.w, A.w)
        FMA4(acc0, x0.x, w0); FMA4(acc1, x1.x, w0); FMA4(acc2, x2.x, w0); FMA4(acc3, x3.x, w0);
        FMA4(acc0, x0.y, w1); FMA4(acc1, x1.y, w1); FMA4(acc2, x2.y, w1); FMA4(acc3, x3.y, w1);
        FMA4(acc0, x0.z, w2); FMA4(acc1, x1.z, w2); FMA4(acc2, x2.z, w2); FMA4(acc3, x3.z, w2);
        FMA4(acc0, x0.w, w3); FMA4(acc1, x1.w, w3); FMA4(acc2, x2.w, w3); FMA4(acc3, x3.w, w3);
#undef FMA4
    }

    // epilogue: store H tile + per-head attention logits
    int hh = cg >> 1;
    float4 as4 = ((const float4*)a_src)[cg];
    float4 ad4 = ((const float4*)a_dst)[cg];
    float4 accs[4] = {acc0, acc1, acc2, acc3};
#pragma unroll
    for (int i = 0; i < 4; ++i) {
        int r = r0 + rbase + i;
        if (r < nrows) {
            ((float4*)H)[r * 16 + cg] = accs[i];
            float ps = accs[i].x * as4.x + accs[i].y * as4.y +
                       accs[i].z * as4.z + accs[i].w * as4.w;
            float pd = accs[i].x * ad4.x + accs[i].y * ad4.y +
                       accs[i].z * ad4.z + accs[i].w * ad4.w;
            ps += __shfl_xor(ps, 1);
            pd += __shfl_xor(pd, 1);
            if ((cg & 1) == 0) {
                ALs[r * 8 + hh] = ps;
                ALd[r * 8 + hh] = pd;
            }
        }
    }
}

// ---------------- GAT aggregation: one wave per dst node, float4 gathers ----------------
// Quarter q (16 lanes) consumes edges j = 4k+q; lane ql holds features 4ql..4ql+3.
// Main path is unpredicated (all j < 4*steps <= m, m wave-uniform), unrolled x8
// for 16 loads in flight. <=3-edge predicated tail per 64-chunk.

__global__ __launch_bounds__(256) void agg_kernel(
    const float* __restrict__ H, const float* __restrict__ ALs, const float* __restrict__ ALd,
    const int* __restrict__ rowptr, const int* __restrict__ col,
    const float* __restrict__ bias, float* __restrict__ Out, int n) {
    int wave = threadIdx.x >> 6, lane = threadIdx.x & 63;
    int d = blockIdx.x * 4 + wave;
    if (d >= n) return;
    int q = lane >> 4, ql = lane & 15;
    int hh = ql >> 1;
    const float4* __restrict__ H4 = (const float4*)H;

    float ad = ALd[d * 8 + hh];
    float4 acc = make_float4(0.f, 0.f, 0.f, 0.f);
    float wsum = 0.f;
    if (q == 0) {  // self loop counted once
        float e = ALs[d * 8 + hh] + ad;
        e = e > 0.f ? e : 0.2f * e;
        float w = __expf(e);
        float4 hv = H4[d * 16 + ql];
        acc.x = w * hv.x; acc.y = w * hv.y; acc.z = w * hv.z; acc.w = w * hv.w;
        wsum = w;
    }

    int beg = rowptr[d], end = rowptr[d + 1];
    for (int base = beg; base < end; base += 64) {
        int m = end - base;
        if (m > 64) m = 64;
        int c = (base + lane < end) ? col[base + lane] : 0;
        int steps = m >> 2;
        int k = 0;
        for (; k + 8 <= steps; k += 8) {
            int j0 = 4 * k + q;
            int s0 = __shfl(c, j0),      s1 = __shfl(c, j0 + 4);
            int s2 = __shfl(c, j0 + 8),  s3 = __shfl(c, j0 + 12);
            int s4 = __shfl(c, j0 + 16), s5 = __shfl(c, j0 + 20);
            int s6 = __shfl(c, j0 + 24), s7 = __shfl(c, j0 + 28);
            float4 h0 = H4[s0 * 16 + ql]; float a0 = ALs[s0 * 8 + hh];
            float4 h1 = H4[s1 * 16 + ql]; float a1 = ALs[s1 * 8 + hh];
            float4 h2 = H4[s2 * 16 + ql]; float a2 = ALs[s2 * 8 + hh];
            float4 h3 = H4[s3 * 16 + ql]; float a3 = ALs[s3 * 8 + hh];
            float4 h4 = H4[s4 * 16 + ql]; float a4 = ALs[s4 * 8 + hh];
            float4 h5 = H4[s5 * 16 + ql]; float a5 = ALs[s5 * 8 + hh];
            float4 h6 = H4[s6 * 16 + ql]; float a6 = ALs[s6 * 8 + hh];
            float4 h7 = H4[s7 * 16 + ql]; float a7 = ALs[s7 * 8 + hh];
            float e0 = a0 + ad; e0 = e0 > 0.f ? e0 : 0.2f * e0; float w0 = __expf(e0);
            float e1 = a1 + ad; e1 = e1 > 0.f ? e1 : 0.2f * e1; float w1 = __expf(e1);
            float e2 = a2 + ad; e2 = e2 > 0.f ? e2 : 0.2f * e2; float w2 = __expf(e2);
            float e3 = a3 + ad; e3 = e3 > 0.f ? e3 : 0.2f * e3; float w3 = __expf(e3);
            float e4 = a4 + ad; e4 = e4 > 0.f ? e4 : 0.2f * e4; float w4 = __expf(e4);
            float e5 = a5 + ad; e5 = e5 > 0.f ? e5 : 0.2f * e5; float w5 = __expf(e5);
            float e6 = a6 + ad; e6 = e6 > 0.f ? e6 : 0.2f * e6; float w6 = __expf(e6);
            float e7 = a7 + ad; e7 = e7 > 0.f ? e7 : 0.2f * e7; float w7 = __expf(e7);
            acc.x = fmaf(w0, h0.x, acc.x); acc.y = fmaf(w0, h0.y, acc.y);
            acc.z = fmaf(w0, h0.z, acc.z); acc.w = fmaf(w0, h0.w, acc.w); wsum += w0;
            acc.x = fmaf(w1, h1.x, acc.x); acc.y = fmaf(w1, h1.y, acc.y);
            acc.z = fmaf(w1, h1.z, acc.z); acc.w = fmaf(w1, h1.w, acc.w); wsum += w1;
            acc.x = fmaf(w2, h2.x, acc.x); acc.y = fmaf(w2, h2.y, acc.y);
            acc.z = fmaf(w2, h2.z, acc.z); acc.w = fmaf(w2, h2.w, acc.w); wsum += w2;
            acc.x = fmaf(w3, h3.x, acc.x); acc.y = fmaf(w3, h3.y, acc.y);
            acc.z = fmaf(w3, h3.z, acc.z); acc.w = fmaf(w3, h3.w, acc.w); wsum += w3;
            acc.x = fmaf(w4, h4.x, acc.x); acc.y = fmaf(w4, h4.y, acc.y);
            acc.z = fmaf(w4, h4.z, acc.z); acc.w = fmaf(w4, h4.w, acc.w); wsum += w4;
            acc.x = fmaf(w5, h5.x, acc.x); acc.y = fmaf(w5, h5.y, acc.y);
            acc.z = fmaf(w5, h5.z, acc.z); acc.w = fmaf(w5, h5.w, acc.w); wsum += w5;
            acc.x = fmaf(w6, h6.x, acc.x); acc.y = fmaf(w6, h6.y, acc.y);
            acc.z = fmaf(w6, h6.z, acc.z); acc.w = fmaf(w6, h6.w, acc.w); wsum += w6;
            acc.x = fmaf(w7, h7.x, acc.x); acc.y = fmaf(w7, h7.y, acc.y);
            acc.z = fmaf(w7, h7.z, acc.z); acc.w = fmaf(w7, h7.w, acc.w); wsum += w7;
        }
        for (; k < steps; ++k) {
            int s = __shfl(c, 4 * k + q);
            float4 hv = H4[s * 16 + ql];
            float a = ALs[s * 8 + hh];
            float e = a + ad; e = e > 0.f ? e : 0.2f * e;
            float w = __expf(e);
            acc.x = fmaf(w, hv.x, acc.x); acc.y = fmaf(w, hv.y, acc.y);
            acc.z = fmaf(w, hv.z, acc.z); acc.w = fmaf(w, hv.w, acc.w);
            wsum += w;
        }
        int t0 = steps << 2;
        if (t0 < m) {  // wave-uniform: <=3 remaining edges
            int j = t0 + q;
            int s = __shfl(c, min(j, m - 1));
            float4 hv = H4[s * 16 + ql];
            float a = ALs[s * 8 + hh];
            float e = a + ad; e = e > 0.f ? e : 0.2f * e;
            float w = j < m ? __expf(e) : 0.f;
            acc.x = fmaf(w, hv.x, acc.x); acc.y = fmaf(w, hv.y, acc.y);
            acc.z = fmaf(w, hv.z, acc.z); acc.w = fmaf(w, hv.w, acc.w);
            wsum += w;
        }
    }

#pragma unroll
    for (int off = 16; off <= 32; off <<= 1) {
        acc.x += __shfl_xor(acc.x, off);
        acc.y += __shfl_xor(acc.y, off);
        acc.z += __shfl_xor(acc.z, off);
        acc.w += __shfl_xor(acc.w, off);
        wsum += __shfl_xor(wsum, off);
    }

    if (q == 0) {
        float inv = 1.f / wsum;
        float4 bv = ((const float4*)bias)[ql];
        float4 o;
        o.x = acc.x * inv + bv.x; o.x = o.x > 0.f ? o.x : expm1f(o.x);
        o.y = acc.y * inv + bv.y; o.y = o.y > 0.f ? o.y : expm1f(o.y);
        o.z = acc.z * inv + bv.z; o.z = o.z > 0.f ? o.z : expm1f(o.z);
        o.w = acc.w * inv + bv.w; o.w = o.w > 0.f ? o.w : expm1f(o.w);
        ((float4*)Out)[d * 16 + ql] = o;
    }
}

// ---------------- global mean pool (batch is sorted) ----------------

__global__ void pool_kernel(const float* __restrict__ H, const int* __restrict__ batch,
                            float* __restrict__ sums, float* __restrict__ cnt, int n) {
    int gw = (int)((blockIdx.x * blockDim.x + threadIdx.x) >> 6);
    int lane = threadIdx.x & 63;
    int n0 = gw * 64;
    if (n0 >= n) return;
    int n1 = min(n0 + 64, n);
    int curb = batch[n0];
    float local = 0.f, c_local = 0.f;
    for (int i = n0; i < n1; ++i) {
        int b = batch[i];
        if (b != curb) {
            atomicAdd(&sums[curb * 64 + lane], local);
            if (lane == 0) atomicAdd(&cnt[curb], c_local);
            local = 0.f;
            c_local = 0.f;
            curb = b;
        }
        local += H[(size_t)i * 64 + lane];
        c_local += 1.f;
    }
    atomicAdd(&sums[curb * 64 + lane], local);
    if (lane == 0) atomicAdd(&cnt[curb], c_local);
}

__global__ void final_kernel(const float* __restrict__ sums, const float* __restrict__ cnt,
                             const float* __restrict__ W, const float* __restrict__ b,
                             float* __restrict__ out) {
    int t = blockIdx.x * blockDim.x + threadIdx.x;
    if (t >= GG * NCLS) return;
    int g = t / NCLS, k = t % NCLS;
    float c = cnt[g];
    if (c < 1.f) c = 1.f;
    float inv = 1.f / c;
    float acc = b[k];
#pragma unroll
    for (int cc = 0; cc < 64; ++cc)
        acc = fmaf(sums[g * 64 + cc] * inv, W[cc * NCLS + k], acc);
    out[t] = acc;
}

// ---------------- launch ----------------

extern "C" void kernel_launch(void* const* d_in, const int* in_sizes, int n_in,
                              void* d_out, int out_size, void* d_ws, size_t ws_size,
                              hipStream_t stream) {
    const float* x    = (const float*)d_in[0];
    const int*   ei   = (const int*)d_in[1];   // [2,E]: src = ei, dst = ei+EE
    const int*   batch = (const int*)d_in[2];
    const float* W1 = (const float*)d_in[3];
    const float* a1s = (const float*)d_in[4];
    const float* a1d = (const float*)d_in[5];
    const float* b1 = (const float*)d_in[6];
    const float* W2 = (const float*)d_in[7];
    const float* a2s = (const float*)d_in[8];
    const float* a2d = (const float*)d_in[9];
    const float* b2 = (const float*)d_in[10];
    const float* W3 = (const float*)d_in[11];
    const float* a3s = (const float*)d_in[12];
    const float* a3d = (const float*)d_in[13];
    const float* b3 = (const float*)d_in[14];
    const float* linW = (const float*)d_in[15];
    const float* linb = (const float*)d_in[16];
    float* out = (float*)d_out;

    char* ws = (char*)d_ws;
    size_t off = 0;
    auto alloc = [&](size_t bytes) -> void* {
        void* p = ws + off;
        off = (off + bytes + 255) & ~(size_t)255;
        return p;
    };
    float* hA     = (float*)alloc((size_t)NN * 64 * 4);
    float* hB     = (float*)alloc((size_t)NN * 64 * 4);
    float* ALs    = (float*)alloc((size_t)NN * 8 * 4);
    float* ALd    = (float*)alloc((size_t)NN * 8 * 4);
    int*   rowptr = (int*)alloc((size_t)(NN + 1) * 4);
    int*   bcnt   = (int*)alloc(256 * 4);
    int*   bfill  = (int*)alloc(256 * 4);
    int*   bbase  = (int*)alloc(257 * 4);
    int*   bsrc   = (int*)alloc((size_t)EE * 4);
    int*   bdst   = (int*)alloc((size_t)EE * 4);
    int*   col    = (int*)alloc((size_t)EE * 4);
    float* sums   = (float*)alloc((size_t)(GG * 64 + GG) * 4);
    float* gcnt   = sums + GG * 64;

    const int NBLK = (NN + 255) / 256;
    const int EB4 = (EE + EPB - 1) / EPB;

    hipMemsetAsync(bcnt, 0, 256 * 4, stream);
    hipMemsetAsync(bfill, 0, 256 * 4, stream);
    bhist_kernel<<<EB4, 256, 0, stream>>>(ei + EE, bcnt, EE);
    bscan_kernel<<<1, 256, 0, stream>>>(bcnt, bbase);
    bscatter_kernel<<<EB4, 256, 0, stream>>>(ei, ei + EE, bfill, bbase, bsrc, bdst, EE);
    bsort_kernel<<<NB, 512, 0, stream>>>(bsrc, bdst, bbase, rowptr, col);

    const int GB = (NN + 63) / 64;   // 1563 blocks, 64 rows each
    const int AB = (NN + 3) / 4;

    gemm_al_kernel<128><<<GB, 256, 0, stream>>>(x, W1, a1s, a1d, hA, ALs, ALd, NN);
    agg_kernel<<<AB, 256, 0, stream>>>(hA, ALs, ALd, rowptr, col, b1, hB, NN);

    gemm_al_kernel<64><<<GB, 256, 0, stream>>>(hB, W2, a2s, a2d, hA, ALs, ALd, NN);
    agg_kernel<<<AB, 256, 0, stream>>>(hA, ALs, ALd, rowptr, col, b2, hB, NN);

    gemm_al_kernel<64><<<GB, 256, 0, stream>>>(hB, W3, a3s, a3d, hA, ALs, ALd, NN);
    agg_kernel<<<AB, 256, 0, stream>>>(hA, ALs, ALd, rowptr, col, b3, hB, NN);

    hipMemsetAsync(sums, 0, (size_t)(GG * 64 + GG) * 4, stream);
    pool_kernel<<<NBLK, 256, 0, stream>>>(hB, batch, sums, gcnt, NN);
    final_kernel<<<3, 256, 0, stream>>>(sums, gcnt, linW, linb, out);
}

// Round 7
// 527.426 us; speedup vs baseline: 1.2224x; 1.0051x over previous
//
#include <hip/hip_runtime.h>
#include <math.h>

#define NN 100000
#define EE 1600000
#define GG 64
#define NCLS 10

#define BSH 8                 // bucket = dst >> 8 (256 nodes per bucket)
#define NB 391                // ceil(NN / 256)
#define EPH 4096              // edges per block in bhist
#define EPS 2048              // edges per block in bscatter
#define CAPS 5120             // bsort LDS staging capacity (ints); mean bucket = 4092

// ---------------- CSR build: two-level counting sort ----------------

__global__ __launch_bounds__(256) void bhist_kernel(const int* __restrict__ dst,
                                                    int* __restrict__ bcnt, int n) {
    __shared__ int h[NB];
    int tid = threadIdx.x;
    for (int i = tid; i < NB; i += 256) h[i] = 0;
    __syncthreads();
    int e0 = blockIdx.x * EPH;
    int e1 = min(e0 + EPH, n);
    for (int e = e0 + tid; e < e1; e += 256) atomicAdd(&h[dst[e] >> BSH], 1);
    __syncthreads();
    for (int i = tid; i < NB; i += 256)
        if (h[i]) atomicAdd(&bcnt[i], h[i]);
}

__global__ __launch_bounds__(512) void bscan_kernel(const int* __restrict__ bcnt,
                                                    int* __restrict__ bbase) {
    __shared__ int s[512];
    int tid = threadIdx.x;
    int v = (tid < NB) ? bcnt[tid] : 0;
    s[tid] = v;
    __syncthreads();
    for (int off = 1; off < 512; off <<= 1) {
        int t = (tid >= off) ? s[tid - off] : 0;
        __syncthreads();
        s[tid] += t;
        __syncthreads();
    }
    if (tid < NB) bbase[tid + 1] = s[tid];
    if (tid == 0) bbase[0] = 0;
}

// scatter edges into bucket-ordered int2 pairs; LDS-staged so global writes are dense runs
__global__ __launch_bounds__(512) void bscatter_kernel(
    const int* __restrict__ src, const int* __restrict__ dst,
    int* __restrict__ bfill, const int* __restrict__ bbase,
    int2* __restrict__ bpair, int n) {
    __shared__ int hist[512], gbase[512], lbase[512], cnt2[512], sc[512];
    __shared__ int2 lsd[EPS];
    __shared__ unsigned short bkt[EPS];
    int tid = threadIdx.x;
    int e0 = blockIdx.x * EPS;
    int e1 = min(e0 + EPS, n);

    hist[tid] = 0;
    cnt2[tid] = 0;
    __syncthreads();
    for (int e = e0 + tid; e < e1; e += 512) atomicAdd(&hist[dst[e] >> BSH], 1);
    __syncthreads();
    sc[tid] = hist[tid];
    __syncthreads();
    for (int off = 1; off < 512; off <<= 1) {
        int t = (tid >= off) ? sc[tid - off] : 0;
        __syncthreads();
        sc[tid] += t;
        __syncthreads();
    }
    lbase[tid] = sc[tid] - hist[tid];
    int go = hist[tid] > 0 ? atomicAdd(&bfill[tid], hist[tid]) : 0;
    gbase[tid] = ((tid < NB) ? bbase[tid] : 0) + go - lbase[tid];  // g = gbase[b] + slot
    __syncthreads();
    for (int e = e0 + tid; e < e1; e += 512) {
        int s = src[e], dd = dst[e];
        int b = dd >> BSH;
        int r = atomicAdd(&cnt2[b], 1);
        int slot = lbase[b] + r;
        lsd[slot] = make_int2(s, dd);
        bkt[slot] = (unsigned short)b;
    }
    __syncthreads();
    int m = e1 - e0;
    for (int i = tid; i < m; i += 512)
        bpair[gbase[bkt[i]] + i] = lsd[i];
}

// per-bucket counting sort -> rowptr + col (256 nodes per bucket, 391 blocks)
__global__ __launch_bounds__(256) void bsort_kernel(
    const int2* __restrict__ bpair, const int* __restrict__ bbase,
    int* __restrict__ rowptr, int* __restrict__ col) {
    __shared__ int cnt[256], cnt2[256], sc[256];
    __shared__ int stage[CAPS];
    int b = blockIdx.x;
    int tid = threadIdx.x;
    int ebeg = bbase[b], eend = bbase[b + 1];
    int n0 = b << BSH;
    int nn = min(256, NN - n0);

    cnt[tid] = 0;
    cnt2[tid] = 0;
    __syncthreads();
    for (int e = ebeg + tid; e < eend; e += 256) atomicAdd(&cnt[bpair[e].y - n0], 1);
    __syncthreads();
    sc[tid] = cnt[tid];
    __syncthreads();
    for (int off = 1; off < 256; off <<= 1) {
        int t = (tid >= off) ? sc[tid - off] : 0;
        __syncthreads();
        sc[tid] += t;
        __syncthreads();
    }
    int excl = sc[tid] - cnt[tid];
    sc[tid] = excl;
    if (tid < nn) rowptr[n0 + tid] = ebeg + excl;
    if (b == NB - 1 && tid == 0) rowptr[NN] = eend;
    __syncthreads();
    int sz = eend - ebeg;
    bool fits = sz <= CAPS;
    for (int e = ebeg + tid; e < eend; e += 256) {
        int2 p = bpair[e];
        int dl = p.y - n0;
        int r = atomicAdd(&cnt2[dl], 1);
        int pos = sc[dl] + r;
        if (fits) stage[pos] = p.x;
        else col[ebeg + pos] = p.x;
    }
    __syncthreads();
    if (fits)
        for (int i = tid; i < sz; i += 256) col[ebeg + i] = stage[i];
}

// ---------------- GEMM h = X @ W (+ attention logits) ----------------
// Register-tiled: block = 64 rows x 64 cols, thread (rg=t>>4, cg=t&15) owns a
// 4x4 tile (16 indep FMA chains). Xs + Ws in LDS.

template <int K>
__global__ __launch_bounds__(256) void gemm_al_kernel(
    const float* __restrict__ X, const float* __restrict__ W,
    const float* __restrict__ a_src, const float* __restrict__ a_dst,
    float* __restrict__ H, float* __restrict__ ALs, float* __restrict__ ALd, int nrows) {
    __shared__ float Xs[64 * K];
    __shared__ float Ws[K * 64];
    int tid = threadIdx.x;
    int r0 = blockIdx.x * 64;

    {
        const float4* Wg = (const float4*)W;
        float4* Ws4 = (float4*)Ws;
        for (int i = tid; i < K * 16; i += 256) Ws4[i] = Wg[i];
    }
    {
        const float4* Xg = (const float4*)(X + (size_t)r0 * K);
        float4* Xs4 = (float4*)Xs;
        const int nq = 64 * K / 4;
        int valid_q = (min(64, nrows - r0) * K) / 4;
        for (int i = tid; i < nq; i += 256)
            Xs4[i] = (i < valid_q) ? Xg[i] : make_float4(0.f, 0.f, 0.f, 0.f);
    }
    __syncthreads();

    int cg = tid & 15, rg = tid >> 4;
    int rbase = rg * 4;
    float4 acc0 = make_float4(0.f, 0.f, 0.f, 0.f);
    float4 acc1 = acc0, acc2 = acc0, acc3 = acc0;

#pragma unroll 2
    for (int k = 0; k < K; k += 4) {
        float4 x0 = *(const float4*)&Xs[(rbase + 0) * K + k];
        float4 x1 = *(const float4*)&Xs[(rbase + 1) * K + k];
        float4 x2 = *(const float4*)&Xs[(rbase + 2) * K + k];
        float4 x3 = *(const float4*)&Xs[(rbase + 3) * K + k];
        float4 w0 = *(const float4*)&Ws[(k + 0) * 64 + 4 * cg];
        float4 w1 = *(const float4*)&Ws[(k + 1) * 64 + 4 * cg];
        float4 w2 = *(const float4*)&Ws[(k + 2) * 64 + 4 * cg];
        float4 w3 = *(const float4*)&Ws[(k + 3) * 64 + 4 * cg];
#define FMA4(A, S, WV) \
        A.x = fmaf(S, WV.x, A.x); A.y = fmaf(S, WV.y, A.y); \
        A.z = fmaf(S, WV.z, A.z); A.w = fmaf(S, WV.w, A.w)
        FMA4(acc0, x0.x, w0); FMA4(acc1, x1.x, w0); FMA4(acc2, x2.x, w0); FMA4(acc3, x3.x, w0);
        FMA4(acc0, x0.y, w1); FMA4(acc1, x1.y, w1); FMA4(acc2, x2.y, w1); FMA4(acc3, x3.y, w1);
        FMA4(acc0, x0.z, w2); FMA4(acc1, x1.z, w2); FMA4(acc2, x2.z, w2); FMA4(acc3, x3.z, w2);
        FMA4(acc0, x0.w, w3); FMA4(acc1, x1.w, w3); FMA4(acc2, x2.w, w3); FMA4(acc3, x3.w, w3);
#undef FMA4
    }

    int hh = cg >> 1;
    float4 as4 = ((const float4*)a_src)[cg];
    float4 ad4 = ((const float4*)a_dst)[cg];
    float4 accs[4] = {acc0, acc1, acc2, acc3};
#pragma unroll
    for (int i = 0; i < 4; ++i) {
        int r = r0 + rbase + i;
        if (r < nrows) {
            ((float4*)H)[r * 16 + cg] = accs[i];
            float ps = accs[i].x * as4.x + accs[i].y * as4.y +
                       accs[i].z * as4.z + accs[i].w * as4.w;
            float pd = accs[i].x * ad4.x + accs[i].y * ad4.y +
                       accs[i].z * ad4.z + accs[i].w * ad4.w;
            ps += __shfl_xor(ps, 1);
            pd += __shfl_xor(pd, 1);
            if ((cg & 1) == 0) {
                ALs[r * 8 + hh] = ps;
                ALd[r * 8 + hh] = pd;
            }
        }
    }
}

// ---------------- GAT aggregation: octet layout ----------------
// One wave per dst node. 8 octets of 8 lanes; octet o handles edges j = 8k+o,
// lane ll (=head) covers features 8ll..8ll+7 (two contiguous float4 loads).
// exp/ALs computed once per (edge, head); ALs reads coalesced within an octet.
// steps-loop unrolled x2 (deg~16 -> exactly one unrolled iteration).

__global__ __launch_bounds__(256, 4) void agg_kernel(
    const float* __restrict__ H, const float* __restrict__ ALs, const float* __restrict__ ALd,
    const int* __restrict__ rowptr, const int* __restrict__ col,
    const float* __restrict__ bias, float* __restrict__ Out, int n) {
    int wave = threadIdx.x >> 6, lane = threadIdx.x & 63;
    int d = blockIdx.x * 4 + wave;
    if (d >= n) return;
    int o = lane >> 3, ll = lane & 7;
    const float4* __restrict__ H4 = (const float4*)H;

    float ad = ALd[d * 8 + ll];
    float4 accA = make_float4(0.f, 0.f, 0.f, 0.f), accB = accA;
    float wsum = 0.f;
    if (o == 0) {  // self loop counted once
        float e = ALs[d * 8 + ll] + ad;
        e = fmaxf(e, 0.2f * e);
        float w = __expf(e);
        float4 hA = H4[d * 16 + 2 * ll], hB = H4[d * 16 + 2 * ll + 1];
        accA.x = w * hA.x; accA.y = w * hA.y; accA.z = w * hA.z; accA.w = w * hA.w;
        accB.x = w * hB.x; accB.y = w * hB.y; accB.z = w * hB.z; accB.w = w * hB.w;
        wsum = w;
    }

    int beg = rowptr[d], end = rowptr[d + 1];
    for (int base = beg; base < end; base += 64) {
        int m = end - base;
        if (m > 64) m = 64;
        int c = (base + lane < end) ? col[base + lane] : 0;
        int steps = m >> 3;
        int k = 0;
        for (; k + 2 <= steps; k += 2) {
            int j0 = 8 * k + o;
            int s0 = __shfl(c, j0), s1 = __shfl(c, j0 + 8);
            float4 hA0 = H4[s0 * 16 + 2 * ll], hB0 = H4[s0 * 16 + 2 * ll + 1];
            float a0 = ALs[s0 * 8 + ll];
            float4 hA1 = H4[s1 * 16 + 2 * ll], hB1 = H4[s1 * 16 + 2 * ll + 1];
            float a1 = ALs[s1 * 8 + ll];
            float e0 = a0 + ad; e0 = fmaxf(e0, 0.2f * e0); float w0 = __expf(e0);
            float e1 = a1 + ad; e1 = fmaxf(e1, 0.2f * e1); float w1 = __expf(e1);
            accA.x = fmaf(w0, hA0.x, accA.x); accA.y = fmaf(w0, hA0.y, accA.y);
            accA.z = fmaf(w0, hA0.z, accA.z); accA.w = fmaf(w0, hA0.w, accA.w);
            accB.x = fmaf(w0, hB0.x, accB.x); accB.y = fmaf(w0, hB0.y, accB.y);
            accB.z = fmaf(w0, hB0.z, accB.z); accB.w = fmaf(w0, hB0.w, accB.w);
            wsum += w0;
            accA.x = fmaf(w1, hA1.x, accA.x); accA.y = fmaf(w1, hA1.y, accA.y);
            accA.z = fmaf(w1, hA1.z, accA.z); accA.w = fmaf(w1, hA1.w, accA.w);
            accB.x = fmaf(w1, hB1.x, accB.x); accB.y = fmaf(w1, hB1.y, accB.y);
            accB.z = fmaf(w1, hB1.z, accB.z); accB.w = fmaf(w1, hB1.w, accB.w);
            wsum += w1;
        }
        for (; k < steps; ++k) {
            int s = __shfl(c, 8 * k + o);
            float4 hA = H4[s * 16 + 2 * ll], hB = H4[s * 16 + 2 * ll + 1];
            float a = ALs[s * 8 + ll];
            float e = a + ad; e = fmaxf(e, 0.2f * e);
            float w = __expf(e);
            accA.x = fmaf(w, hA.x, accA.x); accA.y = fmaf(w, hA.y, accA.y);
            accA.z = fmaf(w, hA.z, accA.z); accA.w = fmaf(w, hA.w, accA.w);
            accB.x = fmaf(w, hB.x, accB.x); accB.y = fmaf(w, hB.y, accB.y);
            accB.z = fmaf(w, hB.z, accB.z); accB.w = fmaf(w, hB.w, accB.w);
            wsum += w;
        }
        int t0 = steps << 3;
        if (t0 < m) {  // wave-uniform: <=7 remaining edges
            int j = t0 + o;
            int s = __shfl(c, min(j, m - 1));
            float4 hA = H4[s * 16 + 2 * ll], hB = H4[s * 16 + 2 * ll + 1];
            float a = ALs[s * 8 + ll];
            float e = a + ad; e = fmaxf(e, 0.2f * e);
            float w = (j < m) ? __expf(e) : 0.f;
            accA.x = fmaf(w, hA.x, accA.x); accA.y = fmaf(w, hA.y, accA.y);
            accA.z = fmaf(w, hA.z, accA.z); accA.w = fmaf(w, hA.w, accA.w);
            accB.x = fmaf(w, hB.x, accB.x); accB.y = fmaf(w, hB.y, accB.y);
            accB.z = fmaf(w, hB.z, accB.z); accB.w = fmaf(w, hB.w, accB.w);
            wsum += w;
        }
    }

    // merge octets: 3 rounds across lanes l^8, l^16, l^32
#pragma unroll
    for (int off = 8; off <= 32; off <<= 1) {
        accA.x += __shfl_xor(accA.x, off); accA.y += __shfl_xor(accA.y, off);
        accA.z += __shfl_xor(accA.z, off); accA.w += __shfl_xor(accA.w, off);
        accB.x += __shfl_xor(accB.x, off); accB.y += __shfl_xor(accB.y, off);
        accB.z += __shfl_xor(accB.z, off); accB.w += __shfl_xor(accB.w, off);
        wsum += __shfl_xor(wsum, off);
    }

    if (o == 0) {
        float inv = 1.f / wsum;
        float4 bA = ((const float4*)bias)[2 * ll];
        float4 bB = ((const float4*)bias)[2 * ll + 1];
        float4 oA, oB;
        oA.x = accA.x * inv + bA.x; oA.x = oA.x > 0.f ? oA.x : expm1f(oA.x);
        oA.y = accA.y * inv + bA.y; oA.y = oA.y > 0.f ? oA.y : expm1f(oA.y);
        oA.z = accA.z * inv + bA.z; oA.z = oA.z > 0.f ? oA.z : expm1f(oA.z);
        oA.w = accA.w * inv + bA.w; oA.w = oA.w > 0.f ? oA.w : expm1f(oA.w);
        oB.x = accB.x * inv + bB.x; oB.x = oB.x > 0.f ? oB.x : expm1f(oB.x);
        oB.y = accB.y * inv + bB.y; oB.y = oB.y > 0.f ? oB.y : expm1f(oB.y);
        oB.z = accB.z * inv + bB.z; oB.z = oB.z > 0.f ? oB.z : expm1f(oB.z);
        oB.w = accB.w * inv + bB.w; oB.w = oB.w > 0.f ? oB.w : expm1f(oB.w);
        ((float4*)Out)[d * 16 + 2 * ll] = oA;
        ((float4*)Out)[d * 16 + 2 * ll + 1] = oB;
    }
}

// ---------------- global mean pool (batch is sorted) ----------------

__global__ void pool_kernel(const float* __restrict__ H, const int* __restrict__ batch,
                            float* __restrict__ sums, float* __restrict__ cnt, int n) {
    int gw = (int)((blockIdx.x * blockDim.x + threadIdx.x) >> 6);
    int lane = threadIdx.x & 63;
    int n0 = gw * 64;
    if (n0 >= n) return;
    int n1 = min(n0 + 64, n);
    int curb = batch[n0];
    float local = 0.f, c_local = 0.f;
    for (int i = n0; i < n1; ++i) {
        int b = batch[i];
        if (b != curb) {
            atomicAdd(&sums[curb * 64 + lane], local);
            if (lane == 0) atomicAdd(&cnt[curb], c_local);
            local = 0.f;
            c_local = 0.f;
            curb = b;
        }
        local += H[(size_t)i * 64 + lane];
        c_local += 1.f;
    }
    atomicAdd(&sums[curb * 64 + lane], local);
    if (lane == 0) atomicAdd(&cnt[curb], c_local);
}

__global__ void final_kernel(const float* __restrict__ sums, const float* __restrict__ cnt,
                             const float* __restrict__ W, const float* __restrict__ b,
                             float* __restrict__ out) {
    int t = blockIdx.x * blockDim.x + threadIdx.x;
    if (t >= GG * NCLS) return;
    int g = t / NCLS, k = t % NCLS;
    float c = cnt[g];
    if (c < 1.f) c = 1.f;
    float inv = 1.f / c;
    float acc = b[k];
#pragma unroll
    for (int cc = 0; cc < 64; ++cc)
        acc = fmaf(sums[g * 64 + cc] * inv, W[cc * NCLS + k], acc);
    out[t] = acc;
}

// ---------------- launch ----------------

extern "C" void kernel_launch(void* const* d_in, const int* in_sizes, int n_in,
                              void* d_out, int out_size, void* d_ws, size_t ws_size,
                              hipStream_t stream) {
    const float* x    = (const float*)d_in[0];
    const int*   ei   = (const int*)d_in[1];   // [2,E]: src = ei, dst = ei+EE
    const int*   batch = (const int*)d_in[2];
    const float* W1 = (const float*)d_in[3];
    const float* a1s = (const float*)d_in[4];
    const float* a1d = (const float*)d_in[5];
    const float* b1 = (const float*)d_in[6];
    const float* W2 = (const float*)d_in[7];
    const float* a2s = (const float*)d_in[8];
    const float* a2d = (const float*)d_in[9];
    const float* b2 = (const float*)d_in[10];
    const float* W3 = (const float*)d_in[11];
    const float* a3s = (const float*)d_in[12];
    const float* a3d = (const float*)d_in[13];
    const float* b3 = (const float*)d_in[14];
    const float* linW = (const float*)d_in[15];
    const float* linb = (const float*)d_in[16];
    float* out = (float*)d_out;

    char* ws = (char*)d_ws;
    size_t off = 0;
    auto alloc = [&](size_t bytes) -> void* {
        void* p = ws + off;
        off = (off + bytes + 255) & ~(size_t)255;
        return p;
    };
    float* hA     = (float*)alloc((size_t)NN * 64 * 4);
    float* hB     = (float*)alloc((size_t)NN * 64 * 4);
    float* ALs    = (float*)alloc((size_t)NN * 8 * 4);
    float* ALd    = (float*)alloc((size_t)NN * 8 * 4);
    int*   rowptr = (int*)alloc((size_t)(NN + 1) * 4);
    int*   bcnt   = (int*)alloc(NB * 4);
    int*   bfill  = (int*)alloc(NB * 4);
    int*   bbase  = (int*)alloc((NB + 1) * 4);
    int2*  bpair  = (int2*)alloc((size_t)EE * 8);
    int*   col    = (int*)alloc((size_t)EE * 4);
    float* sums   = (float*)alloc((size_t)(GG * 64 + GG) * 4);
    float* gcnt   = sums + GG * 64;

    const int NBLK = (NN + 255) / 256;
    const int HB = (EE + EPH - 1) / EPH;   // 391
    const int SB = (EE + EPS - 1) / EPS;   // 782

    hipMemsetAsync(bcnt, 0, NB * 4, stream);
    hipMemsetAsync(bfill, 0, NB * 4, stream);
    bhist_kernel<<<HB, 256, 0, stream>>>(ei + EE, bcnt, EE);
    bscan_kernel<<<1, 512, 0, stream>>>(bcnt, bbase);
    bscatter_kernel<<<SB, 512, 0, stream>>>(ei, ei + EE, bfill, bbase, bpair, EE);
    bsort_kernel<<<NB, 256, 0, stream>>>(bpair, bbase, rowptr, col);

    const int GB = (NN + 63) / 64;   // 1563 blocks, 64 rows each
    const int AB = (NN + 3) / 4;

    gemm_al_kernel<128><<<GB, 256, 0, stream>>>(x, W1, a1s, a1d, hA, ALs, ALd, NN);
    agg_kernel<<<AB, 256, 0, stream>>>(hA, ALs, ALd, rowptr, col, b1, hB, NN);

    gemm_al_kernel<64><<<GB, 256, 0, stream>>>(hB, W2, a2s, a2d, hA, ALs, ALd, NN);
    agg_kernel<<<AB, 256, 0, stream>>>(hA, ALs, ALd, rowptr, col, b2, hB, NN);

    gemm_al_kernel<64><<<GB, 256, 0, stream>>>(hB, W3, a3s, a3d, hA, ALs, ALd, NN);
    agg_kernel<<<AB, 256, 0, stream>>>(hA, ALs, ALd, rowptr, col, b3, hB, NN);

    hipMemsetAsync(sums, 0, (size_t)(GG * 64 + GG) * 4, stream);
    pool_kernel<<<NBLK, 256, 0, stream>>>(hB, batch, sums, gcnt, NN);
    final_kernel<<<3, 256, 0, stream>>>(sums, gcnt, linW, linb, out);
}

// Round 8
// 433.360 us; speedup vs baseline: 1.4877x; 1.2171x over previous
//
#include <hip/hip_runtime.h>
#include <math.h>

#define NN 100000
#define EE 1600000
#define GG 64
#define NCLS 10

#define BSH 8                 // bucket = dst >> 8 (256 nodes per bucket)
#define NB 391                // ceil(NN / 256)
#define EPH 4096              // edges per block in bhist
#define EPS 4096              // edges per block in bscatter
#define CAPS 5120             // bsort LDS staging capacity (ints); mean bucket = 4092

typedef unsigned int uint32;
typedef unsigned short ushort16;

__device__ __forceinline__ unsigned short f2bf(float f) {
    unsigned u = __float_as_uint(f);
    unsigned r = (u + 0x7fffu + ((u >> 16) & 1u)) >> 16;   // RNE
    return (unsigned short)r;
}

// ---------------- CSR build: two-level counting sort ----------------

__global__ __launch_bounds__(256) void bhist_kernel(const int* __restrict__ dst,
                                                    int* __restrict__ bcnt, int n) {
    __shared__ int h[NB];
    int tid = threadIdx.x;
    for (int i = tid; i < NB; i += 256) h[i] = 0;
    __syncthreads();
    int e0 = blockIdx.x * EPH;
    int e1 = min(e0 + EPH, n);
    for (int e = e0 + tid; e < e1; e += 256) atomicAdd(&h[dst[e] >> BSH], 1);
    __syncthreads();
    for (int i = tid; i < NB; i += 256)
        if (h[i]) atomicAdd(&bcnt[i], h[i]);
}

__global__ __launch_bounds__(512) void bscan_kernel(const int* __restrict__ bcnt,
                                                    int* __restrict__ bbase) {
    __shared__ int s[512];
    int tid = threadIdx.x;
    int v = (tid < NB) ? bcnt[tid] : 0;
    s[tid] = v;
    __syncthreads();
    for (int off = 1; off < 512; off <<= 1) {
        int t = (tid >= off) ? s[tid - off] : 0;
        __syncthreads();
        s[tid] += t;
        __syncthreads();
    }
    if (tid < NB) bbase[tid + 1] = s[tid];
    if (tid == 0) bbase[0] = 0;
}

// scatter edges into bucket-ordered packed words (src<<8 | dst&255);
// LDS-staged so global writes are dense runs (~21 x 4B per bucket per block)
__global__ __launch_bounds__(512) void bscatter_kernel(
    const int* __restrict__ src, const int* __restrict__ dst,
    int* __restrict__ bfill, const int* __restrict__ bbase,
    uint32* __restrict__ bpack, int n) {
    __shared__ int hist[512], gbase[512], lbase[512], cnt2[512], sc[512];
    __shared__ uint32 lsd[EPS];
    __shared__ unsigned short bkt[EPS];
    int tid = threadIdx.x;
    int e0 = blockIdx.x * EPS;
    int e1 = min(e0 + EPS, n);

    hist[tid] = 0;
    cnt2[tid] = 0;
    __syncthreads();
    for (int e = e0 + tid; e < e1; e += 512) atomicAdd(&hist[dst[e] >> BSH], 1);
    __syncthreads();
    sc[tid] = hist[tid];
    __syncthreads();
    for (int off = 1; off < 512; off <<= 1) {
        int t = (tid >= off) ? sc[tid - off] : 0;
        __syncthreads();
        sc[tid] += t;
        __syncthreads();
    }
    lbase[tid] = sc[tid] - hist[tid];
    int go = hist[tid] > 0 ? atomicAdd(&bfill[tid], hist[tid]) : 0;
    gbase[tid] = ((tid < NB) ? bbase[tid] : 0) + go - lbase[tid];  // g = gbase[b] + slot
    __syncthreads();
    for (int e = e0 + tid; e < e1; e += 512) {
        int s = src[e], dd = dst[e];
        int b = dd >> BSH;
        int r = atomicAdd(&cnt2[b], 1);
        int slot = lbase[b] + r;
        lsd[slot] = ((uint32)s << 8) | (uint32)(dd & 255);
        bkt[slot] = (unsigned short)b;
    }
    __syncthreads();
    int m = e1 - e0;
    for (int i = tid; i < m; i += 512)
        bpack[gbase[bkt[i]] + i] = lsd[i];
}

// per-bucket counting sort -> rowptr + col (256 nodes per bucket, 391 blocks)
__global__ __launch_bounds__(256) void bsort_kernel(
    const uint32* __restrict__ bpack, const int* __restrict__ bbase,
    int* __restrict__ rowptr, int* __restrict__ col) {
    __shared__ int cnt[256], cnt2[256], sc[256];
    __shared__ int stage[CAPS];
    int b = blockIdx.x;
    int tid = threadIdx.x;
    int ebeg = bbase[b], eend = bbase[b + 1];
    int n0 = b << BSH;
    int nn = min(256, NN - n0);

    cnt[tid] = 0;
    cnt2[tid] = 0;
    __syncthreads();
    for (int e = ebeg + tid; e < eend; e += 256) atomicAdd(&cnt[bpack[e] & 255u], 1);
    __syncthreads();
    sc[tid] = cnt[tid];
    __syncthreads();
    for (int off = 1; off < 256; off <<= 1) {
        int t = (tid >= off) ? sc[tid - off] : 0;
        __syncthreads();
        sc[tid] += t;
        __syncthreads();
    }
    int excl = sc[tid] - cnt[tid];
    sc[tid] = excl;
    if (tid < nn) rowptr[n0 + tid] = ebeg + excl;
    if (b == NB - 1 && tid == 0) rowptr[NN] = eend;
    __syncthreads();
    int sz = eend - ebeg;
    bool fits = sz <= CAPS;
    for (int e = ebeg + tid; e < eend; e += 256) {
        uint32 p = bpack[e];
        int dl = (int)(p & 255u);
        int r = atomicAdd(&cnt2[dl], 1);
        int pos = sc[dl] + r;
        if (fits) stage[pos] = (int)(p >> 8);
        else col[ebeg + pos] = (int)(p >> 8);
    }
    __syncthreads();
    if (fits)
        for (int i = tid; i < sz; i += 256) col[ebeg + i] = stage[i];
}

// ---------------- GEMM h = X @ W (+ attention logits), bf16 H output ----------------
// Register-tiled: block = 64 rows x 64 cols, thread (rg=t>>4, cg=t&15) owns a
// 4x4 tile (16 indep FMA chains). Xs + Ws in LDS.

template <int K>
__global__ __launch_bounds__(256) void gemm_al_kernel(
    const float* __restrict__ X, const float* __restrict__ W,
    const float* __restrict__ a_src, const float* __restrict__ a_dst,
    unsigned short* __restrict__ H, float* __restrict__ ALs, float* __restrict__ ALd,
    int nrows) {
    __shared__ float Xs[64 * K];
    __shared__ float Ws[K * 64];
    int tid = threadIdx.x;
    int r0 = blockIdx.x * 64;

    {
        const float4* Wg = (const float4*)W;
        float4* Ws4 = (float4*)Ws;
        for (int i = tid; i < K * 16; i += 256) Ws4[i] = Wg[i];
    }
    {
        const float4* Xg = (const float4*)(X + (size_t)r0 * K);
        float4* Xs4 = (float4*)Xs;
        const int nq = 64 * K / 4;
        int valid_q = (min(64, nrows - r0) * K) / 4;
        for (int i = tid; i < nq; i += 256)
            Xs4[i] = (i < valid_q) ? Xg[i] : make_float4(0.f, 0.f, 0.f, 0.f);
    }
    __syncthreads();

    int cg = tid & 15, rg = tid >> 4;
    int rbase = rg * 4;
    float4 acc0 = make_float4(0.f, 0.f, 0.f, 0.f);
    float4 acc1 = acc0, acc2 = acc0, acc3 = acc0;

#pragma unroll 2
    for (int k = 0; k < K; k += 4) {
        float4 x0 = *(const float4*)&Xs[(rbase + 0) * K + k];
        float4 x1 = *(const float4*)&Xs[(rbase + 1) * K + k];
        float4 x2 = *(const float4*)&Xs[(rbase + 2) * K + k];
        float4 x3 = *(const float4*)&Xs[(rbase + 3) * K + k];
        float4 w0 = *(const float4*)&Ws[(k + 0) * 64 + 4 * cg];
        float4 w1 = *(const float4*)&Ws[(k + 1) * 64 + 4 * cg];
        float4 w2 = *(const float4*)&Ws[(k + 2) * 64 + 4 * cg];
        float4 w3 = *(const float4*)&Ws[(k + 3) * 64 + 4 * cg];
#define FMA4(A, S, WV) \
        A.x = fmaf(S, WV.x, A.x); A.y = fmaf(S, WV.y, A.y); \
        A.z = fmaf(S, WV.z, A.z); A.w = fmaf(S, WV.w, A.w)
        FMA4(acc0, x0.x, w0); FMA4(acc1, x1.x, w0); FMA4(acc2, x2.x, w0); FMA4(acc3, x3.x, w0);
        FMA4(acc0, x0.y, w1); FMA4(acc1, x1.y, w1); FMA4(acc2, x2.y, w1); FMA4(acc3, x3.y, w1);
        FMA4(acc0, x0.z, w2); FMA4(acc1, x1.z, w2); FMA4(acc2, x2.z, w2); FMA4(acc3, x3.z, w2);
        FMA4(acc0, x0.w, w3); FMA4(acc1, x1.w, w3); FMA4(acc2, x2.w, w3); FMA4(acc3, x3.w, w3);
#undef FMA4
    }

    int hh = cg >> 1;
    float4 as4 = ((const float4*)a_src)[cg];
    float4 ad4 = ((const float4*)a_dst)[cg];
    float4 accs[4] = {acc0, acc1, acc2, acc3};
#pragma unroll
    for (int i = 0; i < 4; ++i) {
        int r = r0 + rbase + i;
        if (r < nrows) {
            ushort4 p;
            p.x = f2bf(accs[i].x); p.y = f2bf(accs[i].y);
            p.z = f2bf(accs[i].z); p.w = f2bf(accs[i].w);
            ((ushort4*)H)[(size_t)r * 16 + cg] = p;   // row = 64 bf16 = 16 ushort4
            float ps = accs[i].x * as4.x + accs[i].y * as4.y +
                       accs[i].z * as4.z + accs[i].w * as4.w;
            float pd = accs[i].x * ad4.x + accs[i].y * ad4.y +
                       accs[i].z * ad4.z + accs[i].w * ad4.w;
            ps += __shfl_xor(ps, 1);
            pd += __shfl_xor(pd, 1);
            if ((cg & 1) == 0) {
                ALs[r * 8 + hh] = ps;
                ALd[r * 8 + hh] = pd;
            }
        }
    }
}

// ---------------- GAT aggregation: lane-per-(node,head), bf16 H gather ----------------
// Wave = 8 nodes x 8 heads. Lane (slot,head) owns features head*8..head*8+7 of node
// slot and serially walks its node's edge list (no cross-lane merge, no shfl).
// One uint4 load per edge per lane = 8 bf16 features (128B/row total).
// Edge loop unrolled x2 for 2 independent load chains.

__global__ __launch_bounds__(256, 6) void agg_kernel(
    const unsigned short* __restrict__ H, const float* __restrict__ ALs,
    const float* __restrict__ ALd, const int* __restrict__ rowptr,
    const int* __restrict__ col, const float* __restrict__ bias,
    float* __restrict__ Out, int n) {
    int tid = threadIdx.x;
    int lane = tid & 63;
    int slot = lane >> 3, head = lane & 7;
    int wid = blockIdx.x * 4 + (tid >> 6);
    int d = wid * 8 + slot;
    bool active = d < n;
    if (!active) d = n - 1;
    const uint4* __restrict__ Hq = (const uint4*)H;   // row = 8 uint4

    float ad = ALd[d * 8 + head];
    float acc0 = 0.f, acc1 = 0.f, acc2 = 0.f, acc3 = 0.f;
    float acc4 = 0.f, acc5 = 0.f, acc6 = 0.f, acc7 = 0.f;
    float wsum = 0.f;

#define FMA8(U, W) { \
    acc0 = fmaf(W, __uint_as_float((U).x << 16), acc0); \
    acc1 = fmaf(W, __uint_as_float((U).x & 0xffff0000u), acc1); \
    acc2 = fmaf(W, __uint_as_float((U).y << 16), acc2); \
    acc3 = fmaf(W, __uint_as_float((U).y & 0xffff0000u), acc3); \
    acc4 = fmaf(W, __uint_as_float((U).z << 16), acc4); \
    acc5 = fmaf(W, __uint_as_float((U).z & 0xffff0000u), acc5); \
    acc6 = fmaf(W, __uint_as_float((U).w << 16), acc6); \
    acc7 = fmaf(W, __uint_as_float((U).w & 0xffff0000u), acc7); }

    {   // self loop
        uint4 u = Hq[(size_t)d * 8 + head];
        float e = ALs[d * 8 + head] + ad;
        e = fmaxf(e, 0.2f * e);
        float w = __expf(e);
        FMA8(u, w);
        wsum = w;
    }

    int k = rowptr[d], re = rowptr[d + 1];
    for (; k + 2 <= re; k += 2) {
        int s0 = col[k], s1 = col[k + 1];
        uint4 u0 = Hq[(size_t)s0 * 8 + head];
        uint4 u1 = Hq[(size_t)s1 * 8 + head];
        float a0 = ALs[s0 * 8 + head];
        float a1 = ALs[s1 * 8 + head];
        float e0 = a0 + ad; e0 = fmaxf(e0, 0.2f * e0); float w0 = __expf(e0);
        float e1 = a1 + ad; e1 = fmaxf(e1, 0.2f * e1); float w1 = __expf(e1);
        FMA8(u0, w0);
        FMA8(u1, w1);
        wsum += w0 + w1;
    }
    if (k < re) {
        int s = col[k];
        uint4 u = Hq[(size_t)s * 8 + head];
        float a = ALs[s * 8 + head];
        float e = a + ad; e = fmaxf(e, 0.2f * e);
        float w = __expf(e);
        FMA8(u, w);
        wsum += w;
    }
#undef FMA8

    if (active) {
        float inv = 1.f / wsum;
        float4 b0 = ((const float4*)bias)[head * 2];
        float4 b1 = ((const float4*)bias)[head * 2 + 1];
        float4 o0, o1;
        o0.x = fmaf(acc0, inv, b0.x); o0.x = o0.x > 0.f ? o0.x : expm1f(o0.x);
        o0.y = fmaf(acc1, inv, b0.y); o0.y = o0.y > 0.f ? o0.y : expm1f(o0.y);
        o0.z = fmaf(acc2, inv, b0.z); o0.z = o0.z > 0.f ? o0.z : expm1f(o0.z);
        o0.w = fmaf(acc3, inv, b0.w); o0.w = o0.w > 0.f ? o0.w : expm1f(o0.w);
        o1.x = fmaf(acc4, inv, b1.x); o1.x = o1.x > 0.f ? o1.x : expm1f(o1.x);
        o1.y = fmaf(acc5, inv, b1.y); o1.y = o1.y > 0.f ? o1.y : expm1f(o1.y);
        o1.z = fmaf(acc6, inv, b1.z); o1.z = o1.z > 0.f ? o1.z : expm1f(o1.z);
        o1.w = fmaf(acc7, inv, b1.w); o1.w = o1.w > 0.f ? o1.w : expm1f(o1.w);
        ((float4*)Out)[(size_t)d * 16 + head * 2] = o0;
        ((float4*)Out)[(size_t)d * 16 + head * 2 + 1] = o1;
    }
}

// ---------------- global mean pool (batch is sorted) ----------------

__global__ void pool_kernel(const float* __restrict__ H, const int* __restrict__ batch,
                            float* __restrict__ sums, float* __restrict__ cnt, int n) {
    int gw = (int)((blockIdx.x * blockDim.x + threadIdx.x) >> 6);
    int lane = threadIdx.x & 63;
    int n0 = gw * 64;
    if (n0 >= n) return;
    int n1 = min(n0 + 64, n);
    int curb = batch[n0];
    float local = 0.f, c_local = 0.f;
    for (int i = n0; i < n1; ++i) {
        int b = batch[i];
        if (b != curb) {
            atomicAdd(&sums[curb * 64 + lane], local);
            if (lane == 0) atomicAdd(&cnt[curb], c_local);
            local = 0.f;
            c_local = 0.f;
            curb = b;
        }
        local += H[(size_t)i * 64 + lane];
        c_local += 1.f;
    }
    atomicAdd(&sums[curb * 64 + lane], local);
    if (lane == 0) atomicAdd(&cnt[curb], c_local);
}

__global__ void final_kernel(const float* __restrict__ sums, const float* __restrict__ cnt,
                             const float* __restrict__ W, const float* __restrict__ b,
                             float* __restrict__ out) {
    int t = blockIdx.x * blockDim.x + threadIdx.x;
    if (t >= GG * NCLS) return;
    int g = t / NCLS, k = t % NCLS;
    float c = cnt[g];
    if (c < 1.f) c = 1.f;
    float inv = 1.f / c;
    float acc = b[k];
#pragma unroll
    for (int cc = 0; cc < 64; ++cc)
        acc = fmaf(sums[g * 64 + cc] * inv, W[cc * NCLS + k], acc);
    out[t] = acc;
}

// ---------------- launch ----------------

extern "C" void kernel_launch(void* const* d_in, const int* in_sizes, int n_in,
                              void* d_out, int out_size, void* d_ws, size_t ws_size,
                              hipStream_t stream) {
    const float* x    = (const float*)d_in[0];
    const int*   ei   = (const int*)d_in[1];   // [2,E]: src = ei, dst = ei+EE
    const int*   batch = (const int*)d_in[2];
    const float* W1 = (const float*)d_in[3];
    const float* a1s = (const float*)d_in[4];
    const float* a1d = (const float*)d_in[5];
    const float* b1 = (const float*)d_in[6];
    const float* W2 = (const float*)d_in[7];
    const float* a2s = (const float*)d_in[8];
    const float* a2d = (const float*)d_in[9];
    const float* b2 = (const float*)d_in[10];
    const float* W3 = (const float*)d_in[11];
    const float* a3s = (const float*)d_in[12];
    const float* a3d = (const float*)d_in[13];
    const float* b3 = (const float*)d_in[14];
    const float* linW = (const float*)d_in[15];
    const float* linb = (const float*)d_in[16];
    float* out = (float*)d_out;

    char* ws = (char*)d_ws;
    size_t off = 0;
    auto alloc = [&](size_t bytes) -> void* {
        void* p = ws + off;
        off = (off + bytes + 255) & ~(size_t)255;
        return p;
    };
    unsigned short* hBf = (unsigned short*)alloc((size_t)NN * 64 * 2);  // bf16 projected features
    float* hF     = (float*)alloc((size_t)NN * 64 * 4);                  // fp32 layer outputs
    float* ALs    = (float*)alloc((size_t)NN * 8 * 4);
    float* ALd    = (float*)alloc((size_t)NN * 8 * 4);
    int*   rowptr = (int*)alloc((size_t)(NN + 1) * 4);
    int*   bcnt   = (int*)alloc(NB * 4);
    int*   bfill  = (int*)alloc(NB * 4);
    int*   bbase  = (int*)alloc((NB + 1) * 4);
    uint32* bpack = (uint32*)alloc((size_t)EE * 4);
    int*   col    = (int*)alloc((size_t)EE * 4);
    float* sums   = (float*)alloc((size_t)(GG * 64 + GG) * 4);
    float* gcnt   = sums + GG * 64;

    const int NBLK = (NN + 255) / 256;
    const int HB = (EE + EPH - 1) / EPH;   // 391
    const int SB = (EE + EPS - 1) / EPS;   // 391

    hipMemsetAsync(bcnt, 0, NB * 4, stream);
    hipMemsetAsync(bfill, 0, NB * 4, stream);
    bhist_kernel<<<HB, 256, 0, stream>>>(ei + EE, bcnt, EE);
    bscan_kernel<<<1, 512, 0, stream>>>(bcnt, bbase);
    bscatter_kernel<<<SB, 512, 0, stream>>>(ei, ei + EE, bfill, bbase, bpack, EE);
    bsort_kernel<<<NB, 256, 0, stream>>>(bpack, bbase, rowptr, col);

    const int GB = (NN + 63) / 64;    // 1563 blocks, 64 rows each
    const int AB = (NN + 31) / 32;    // 3125 blocks, 32 nodes each

    gemm_al_kernel<128><<<GB, 256, 0, stream>>>(x, W1, a1s, a1d, hBf, ALs, ALd, NN);
    agg_kernel<<<AB, 256, 0, stream>>>(hBf, ALs, ALd, rowptr, col, b1, hF, NN);

    gemm_al_kernel<64><<<GB, 256, 0, stream>>>(hF, W2, a2s, a2d, hBf, ALs, ALd, NN);
    agg_kernel<<<AB, 256, 0, stream>>>(hBf, ALs, ALd, rowptr, col, b2, hF, NN);

    gemm_al_kernel<64><<<GB, 256, 0, stream>>>(hF, W3, a3s, a3d, hBf, ALs, ALd, NN);
    agg_kernel<<<AB, 256, 0, stream>>>(hBf, ALs, ALd, rowptr, col, b3, hF, NN);

    hipMemsetAsync(sums, 0, (size_t)(GG * 64 + GG) * 4, stream);
    pool_kernel<<<NBLK, 256, 0, stream>>>(hF, batch, sums, gcnt, NN);
    final_kernel<<<3, 256, 0, stream>>>(sums, gcnt, linW, linb, out);
}

// Round 9
// 429.069 us; speedup vs baseline: 1.5026x; 1.0100x over previous
//
#include <hip/hip_runtime.h>
#include <math.h>

#define NN 100000
#define EE 1600000
#define GG 64
#define NCLS 10

#define BSH 8                 // bucket = dst >> 8 (256 nodes per bucket)
#define NB 391                // ceil(NN / 256)
#define EPH 8192              // edges per block in bhist
#define EPS 4096              // edges per block in bscatter
#define CAPS 5120             // bsort LDS staging capacity (ints); mean bucket = 4092

typedef unsigned int uint32;

__device__ __forceinline__ unsigned short f2bf(float f) {
    unsigned u = __float_as_uint(f);
    unsigned r = (u + 0x7fffu + ((u >> 16) & 1u)) >> 16;   // RNE
    return (unsigned short)r;
}

// ---------------- CSR build: two-level counting sort ----------------

__global__ __launch_bounds__(512) void bhist_kernel(const int* __restrict__ dst,
                                                    int* __restrict__ bcnt, int n) {
    __shared__ int h[NB];
    int tid = threadIdx.x;
    for (int i = tid; i < NB; i += 512) h[i] = 0;
    __syncthreads();
    int e0 = blockIdx.x * EPH;
    int e1 = min(e0 + EPH, n);
    for (int e = e0 + tid; e < e1; e += 512) atomicAdd(&h[dst[e] >> BSH], 1);
    __syncthreads();
    for (int i = tid; i < NB; i += 512)
        if (h[i]) atomicAdd(&bcnt[i], h[i]);
}

__global__ __launch_bounds__(512) void bscan_kernel(const int* __restrict__ bcnt,
                                                    int* __restrict__ bbase) {
    __shared__ int s[512];
    int tid = threadIdx.x;
    int v = (tid < NB) ? bcnt[tid] : 0;
    s[tid] = v;
    __syncthreads();
    for (int off = 1; off < 512; off <<= 1) {
        int t = (tid >= off) ? s[tid - off] : 0;
        __syncthreads();
        s[tid] += t;
        __syncthreads();
    }
    if (tid < NB) bbase[tid + 1] = s[tid];
    if (tid == 0) bbase[0] = 0;
}

// scatter edges into bucket-ordered packed words (src<<8 | dst&255);
// LDS-staged so global writes are dense runs
__global__ __launch_bounds__(512) void bscatter_kernel(
    const int* __restrict__ src, const int* __restrict__ dst,
    int* __restrict__ bfill, const int* __restrict__ bbase,
    uint32* __restrict__ bpack, int n) {
    __shared__ int hist[512], gbase[512], lbase[512], cnt2[512], sc[512];
    __shared__ uint32 lsd[EPS];
    __shared__ unsigned short bkt[EPS];
    int tid = threadIdx.x;
    int e0 = blockIdx.x * EPS;
    int e1 = min(e0 + EPS, n);

    hist[tid] = 0;
    cnt2[tid] = 0;
    __syncthreads();
    for (int e = e0 + tid; e < e1; e += 512) atomicAdd(&hist[dst[e] >> BSH], 1);
    __syncthreads();
    sc[tid] = hist[tid];
    __syncthreads();
    for (int off = 1; off < 512; off <<= 1) {
        int t = (tid >= off) ? sc[tid - off] : 0;
        __syncthreads();
        sc[tid] += t;
        __syncthreads();
    }
    lbase[tid] = sc[tid] - hist[tid];
    int go = hist[tid] > 0 ? atomicAdd(&bfill[tid], hist[tid]) : 0;
    gbase[tid] = ((tid < NB) ? bbase[tid] : 0) + go - lbase[tid];  // g = gbase[b] + slot
    __syncthreads();
    for (int e = e0 + tid; e < e1; e += 512) {
        int s = src[e], dd = dst[e];
        int b = dd >> BSH;
        int r = atomicAdd(&cnt2[b], 1);
        int slot = lbase[b] + r;
        lsd[slot] = ((uint32)s << 8) | (uint32)(dd & 255);
        bkt[slot] = (unsigned short)b;
    }
    __syncthreads();
    int m = e1 - e0;
    for (int i = tid; i < m; i += 512)
        bpack[gbase[bkt[i]] + i] = lsd[i];
}

// per-bucket counting sort -> rowptr + col (256 nodes per bucket, 391 blocks)
__global__ __launch_bounds__(256) void bsort_kernel(
    const uint32* __restrict__ bpack, const int* __restrict__ bbase,
    int* __restrict__ rowptr, int* __restrict__ col) {
    __shared__ int cnt[256], cnt2[256], sc[256];
    __shared__ int stage[CAPS];
    int b = blockIdx.x;
    int tid = threadIdx.x;
    int ebeg = bbase[b], eend = bbase[b + 1];
    int n0 = b << BSH;
    int nn = min(256, NN - n0);

    cnt[tid] = 0;
    cnt2[tid] = 0;
    __syncthreads();
    for (int e = ebeg + tid; e < eend; e += 256) atomicAdd(&cnt[bpack[e] & 255u], 1);
    __syncthreads();
    sc[tid] = cnt[tid];
    __syncthreads();
    for (int off = 1; off < 256; off <<= 1) {
        int t = (tid >= off) ? sc[tid - off] : 0;
        __syncthreads();
        sc[tid] += t;
        __syncthreads();
    }
    int excl = sc[tid] - cnt[tid];
    sc[tid] = excl;
    if (tid < nn) rowptr[n0 + tid] = ebeg + excl;
    if (b == NB - 1 && tid == 0) rowptr[NN] = eend;
    __syncthreads();
    int sz = eend - ebeg;
    bool fits = sz <= CAPS;
    for (int e = ebeg + tid; e < eend; e += 256) {
        uint32 p = bpack[e];
        int dl = (int)(p & 255u);
        int r = atomicAdd(&cnt2[dl], 1);
        int pos = sc[dl] + r;
        if (fits) stage[pos] = (int)(p >> 8);
        else col[ebeg + pos] = (int)(p >> 8);
    }
    __syncthreads();
    if (fits)
        for (int i = tid; i < sz; i += 256) col[ebeg + i] = stage[i];
}

// ---------------- GEMM h = X @ W (+ attention logits), bf16 H output ----------------
// Register-tiled: block = 64 rows x 64 cols, thread (rg=t>>4, cg=t&15) owns a
// 4x4 tile (16 indep FMA chains). Xs + Ws in LDS.

template <int K>
__global__ __launch_bounds__(256) void gemm_al_kernel(
    const float* __restrict__ X, const float* __restrict__ W,
    const float* __restrict__ a_src, const float* __restrict__ a_dst,
    unsigned short* __restrict__ H, float* __restrict__ ALs, float* __restrict__ ALd,
    int nrows) {
    __shared__ float Xs[64 * K];
    __shared__ float Ws[K * 64];
    int tid = threadIdx.x;
    int r0 = blockIdx.x * 64;

    {
        const float4* Wg = (const float4*)W;
        float4* Ws4 = (float4*)Ws;
        for (int i = tid; i < K * 16; i += 256) Ws4[i] = Wg[i];
    }
    {
        const float4* Xg = (const float4*)(X + (size_t)r0 * K);
        float4* Xs4 = (float4*)Xs;
        const int nq = 64 * K / 4;
        int valid_q = (min(64, nrows - r0) * K) / 4;
        for (int i = tid; i < nq; i += 256)
            Xs4[i] = (i < valid_q) ? Xg[i] : make_float4(0.f, 0.f, 0.f, 0.f);
    }
    __syncthreads();

    int cg = tid & 15, rg = tid >> 4;
    int rbase = rg * 4;
    float4 acc0 = make_float4(0.f, 0.f, 0.f, 0.f);
    float4 acc1 = acc0, acc2 = acc0, acc3 = acc0;

#pragma unroll 2
    for (int k = 0; k < K; k += 4) {
        float4 x0 = *(const float4*)&Xs[(rbase + 0) * K + k];
        float4 x1 = *(const float4*)&Xs[(rbase + 1) * K + k];
        float4 x2 = *(const float4*)&Xs[(rbase + 2) * K + k];
        float4 x3 = *(const float4*)&Xs[(rbase + 3) * K + k];
        float4 w0 = *(const float4*)&Ws[(k + 0) * 64 + 4 * cg];
        float4 w1 = *(const float4*)&Ws[(k + 1) * 64 + 4 * cg];
        float4 w2 = *(const float4*)&Ws[(k + 2) * 64 + 4 * cg];
        float4 w3 = *(const float4*)&Ws[(k + 3) * 64 + 4 * cg];
#define FMA4(A, S, WV) \
        A.x = fmaf(S, WV.x, A.x); A.y = fmaf(S, WV.y, A.y); \
        A.z = fmaf(S, WV.z, A.z); A.w = fmaf(S, WV.w, A.w)
        FMA4(acc0, x0.x, w0); FMA4(acc1, x1.x, w0); FMA4(acc2, x2.x, w0); FMA4(acc3, x3.x, w0);
        FMA4(acc0, x0.y, w1); FMA4(acc1, x1.y, w1); FMA4(acc2, x2.y, w1); FMA4(acc3, x3.y, w1);
        FMA4(acc0, x0.z, w2); FMA4(acc1, x1.z, w2); FMA4(acc2, x2.z, w2); FMA4(acc3, x3.z, w2);
        FMA4(acc0, x0.w, w3); FMA4(acc1, x1.w, w3); FMA4(acc2, x2.w, w3); FMA4(acc3, x3.w, w3);
#undef FMA4
    }

    int hh = cg >> 1;
    float4 as4 = ((const float4*)a_src)[cg];
    float4 ad4 = ((const float4*)a_dst)[cg];
    float4 accs[4] = {acc0, acc1, acc2, acc3};
#pragma unroll
    for (int i = 0; i < 4; ++i) {
        int r = r0 + rbase + i;
        if (r < nrows) {
            ushort4 p;
            p.x = f2bf(accs[i].x); p.y = f2bf(accs[i].y);
            p.z = f2bf(accs[i].z); p.w = f2bf(accs[i].w);
            ((ushort4*)H)[(size_t)r * 16 + cg] = p;   // row = 64 bf16 = 16 ushort4
            float ps = accs[i].x * as4.x + accs[i].y * as4.y +
                       accs[i].z * as4.z + accs[i].w * as4.w;
            float pd = accs[i].x * ad4.x + accs[i].y * ad4.y +
                       accs[i].z * ad4.z + accs[i].w * ad4.w;
            ps += __shfl_xor(ps, 1);
            pd += __shfl_xor(pd, 1);
            if ((cg & 1) == 0) {
                ALs[r * 8 + hh] = ps;
                ALd[r * 8 + hh] = pd;
            }
        }
    }
}

// ---------------- GAT aggregation: lane-per-(node,head), bf16 H gather ----------------
// Wave = 8 nodes x 8 heads. Lane (slot,head) owns features head*8..head*8+7 of node
// slot and serially walks its node's edge list. Edge loop unrolled x4:
// 12 independent loads in flight per lane (4 col + 4 uint4 + 4 ALs).

__global__ __launch_bounds__(256, 6) void agg_kernel(
    const unsigned short* __restrict__ H, const float* __restrict__ ALs,
    const float* __restrict__ ALd, const int* __restrict__ rowptr,
    const int* __restrict__ col, const float* __restrict__ bias,
    float* __restrict__ Out, int n) {
    int tid = threadIdx.x;
    int lane = tid & 63;
    int slot = lane >> 3, head = lane & 7;
    int wid = blockIdx.x * 4 + (tid >> 6);
    int d = wid * 8 + slot;
    bool active = d < n;
    if (!active) d = n - 1;
    const uint4* __restrict__ Hq = (const uint4*)H;   // row = 8 uint4

    float ad = ALd[d * 8 + head];
    float acc0 = 0.f, acc1 = 0.f, acc2 = 0.f, acc3 = 0.f;
    float acc4 = 0.f, acc5 = 0.f, acc6 = 0.f, acc7 = 0.f;
    float wsum = 0.f;

#define FMA8(U, W) { \
    acc0 = fmaf(W, __uint_as_float((U).x << 16), acc0); \
    acc1 = fmaf(W, __uint_as_float((U).x & 0xffff0000u), acc1); \
    acc2 = fmaf(W, __uint_as_float((U).y << 16), acc2); \
    acc3 = fmaf(W, __uint_as_float((U).y & 0xffff0000u), acc3); \
    acc4 = fmaf(W, __uint_as_float((U).z << 16), acc4); \
    acc5 = fmaf(W, __uint_as_float((U).z & 0xffff0000u), acc5); \
    acc6 = fmaf(W, __uint_as_float((U).w << 16), acc6); \
    acc7 = fmaf(W, __uint_as_float((U).w & 0xffff0000u), acc7); }

    {   // self loop
        uint4 u = Hq[(size_t)d * 8 + head];
        float e = ALs[d * 8 + head] + ad;
        e = fmaxf(e, 0.2f * e);
        float w = __expf(e);
        FMA8(u, w);
        wsum = w;
    }

    int k = rowptr[d], re = rowptr[d + 1];
    for (; k + 4 <= re; k += 4) {
        int s0 = col[k], s1 = col[k + 1], s2 = col[k + 2], s3 = col[k + 3];
        uint4 u0 = Hq[(size_t)s0 * 8 + head];
        uint4 u1 = Hq[(size_t)s1 * 8 + head];
        uint4 u2 = Hq[(size_t)s2 * 8 + head];
        uint4 u3 = Hq[(size_t)s3 * 8 + head];
        float a0 = ALs[s0 * 8 + head];
        float a1 = ALs[s1 * 8 + head];
        float a2 = ALs[s2 * 8 + head];
        float a3 = ALs[s3 * 8 + head];
        float e0 = a0 + ad; e0 = fmaxf(e0, 0.2f * e0); float w0 = __expf(e0);
        float e1 = a1 + ad; e1 = fmaxf(e1, 0.2f * e1); float w1 = __expf(e1);
        float e2 = a2 + ad; e2 = fmaxf(e2, 0.2f * e2); float w2 = __expf(e2);
        float e3 = a3 + ad; e3 = fmaxf(e3, 0.2f * e3); float w3 = __expf(e3);
        FMA8(u0, w0);
        FMA8(u1, w1);
        FMA8(u2, w2);
        FMA8(u3, w3);
        wsum += (w0 + w1) + (w2 + w3);
    }
    if (k + 2 <= re) {
        int s0 = col[k], s1 = col[k + 1];
        uint4 u0 = Hq[(size_t)s0 * 8 + head];
        uint4 u1 = Hq[(size_t)s1 * 8 + head];
        float a0 = ALs[s0 * 8 + head];
        float a1 = ALs[s1 * 8 + head];
        float e0 = a0 + ad; e0 = fmaxf(e0, 0.2f * e0); float w0 = __expf(e0);
        float e1 = a1 + ad; e1 = fmaxf(e1, 0.2f * e1); float w1 = __expf(e1);
        FMA8(u0, w0);
        FMA8(u1, w1);
        wsum += w0 + w1;
        k += 2;
    }
    if (k < re) {
        int s = col[k];
        uint4 u = Hq[(size_t)s * 8 + head];
        float a = ALs[s * 8 + head];
        float e = a + ad; e = fmaxf(e, 0.2f * e);
        float w = __expf(e);
        FMA8(u, w);
        wsum += w;
    }
#undef FMA8

    if (active) {
        float inv = 1.f / wsum;
        float4 b0 = ((const float4*)bias)[head * 2];
        float4 b1 = ((const float4*)bias)[head * 2 + 1];
        float4 o0, o1;
        o0.x = fmaf(acc0, inv, b0.x); o0.x = o0.x > 0.f ? o0.x : expm1f(o0.x);
        o0.y = fmaf(acc1, inv, b0.y); o0.y = o0.y > 0.f ? o0.y : expm1f(o0.y);
        o0.z = fmaf(acc2, inv, b0.z); o0.z = o0.z > 0.f ? o0.z : expm1f(o0.z);
        o0.w = fmaf(acc3, inv, b0.w); o0.w = o0.w > 0.f ? o0.w : expm1f(o0.w);
        o1.x = fmaf(acc4, inv, b1.x); o1.x = o1.x > 0.f ? o1.x : expm1f(o1.x);
        o1.y = fmaf(acc5, inv, b1.y); o1.y = o1.y > 0.f ? o1.y : expm1f(o1.y);
        o1.z = fmaf(acc6, inv, b1.z); o1.z = o1.z > 0.f ? o1.z : expm1f(o1.z);
        o1.w = fmaf(acc7, inv, b1.w); o1.w = o1.w > 0.f ? o1.w : expm1f(o1.w);
        ((float4*)Out)[(size_t)d * 16 + head * 2] = o0;
        ((float4*)Out)[(size_t)d * 16 + head * 2 + 1] = o1;
    }
}

// ---------------- global mean pool (batch is sorted) ----------------

__global__ void pool_kernel(const float* __restrict__ H, const int* __restrict__ batch,
                            float* __restrict__ sums, float* __restrict__ cnt, int n) {
    int gw = (int)((blockIdx.x * blockDim.x + threadIdx.x) >> 6);
    int lane = threadIdx.x & 63;
    int n0 = gw * 64;
    if (n0 >= n) return;
    int n1 = min(n0 + 64, n);
    int curb = batch[n0];
    float local = 0.f, c_local = 0.f;
    for (int i = n0; i < n1; ++i) {
        int b = batch[i];
        if (b != curb) {
            atomicAdd(&sums[curb * 64 + lane], local);
            if (lane == 0) atomicAdd(&cnt[curb], c_local);
            local = 0.f;
            c_local = 0.f;
            curb = b;
        }
        local += H[(size_t)i * 64 + lane];
        c_local += 1.f;
    }
    atomicAdd(&sums[curb * 64 + lane], local);
    if (lane == 0) atomicAdd(&cnt[curb], c_local);
}

__global__ void final_kernel(const float* __restrict__ sums, const float* __restrict__ cnt,
                             const float* __restrict__ W, const float* __restrict__ b,
                             float* __restrict__ out) {
    int t = blockIdx.x * blockDim.x + threadIdx.x;
    if (t >= GG * NCLS) return;
    int g = t / NCLS, k = t % NCLS;
    float c = cnt[g];
    if (c < 1.f) c = 1.f;
    float inv = 1.f / c;
    float acc = b[k];
#pragma unroll
    for (int cc = 0; cc < 64; ++cc)
        acc = fmaf(sums[g * 64 + cc] * inv, W[cc * NCLS + k], acc);
    out[t] = acc;
}

// ---------------- launch ----------------

extern "C" void kernel_launch(void* const* d_in, const int* in_sizes, int n_in,
                              void* d_out, int out_size, void* d_ws, size_t ws_size,
                              hipStream_t stream) {
    const float* x    = (const float*)d_in[0];
    const int*   ei   = (const int*)d_in[1];   // [2,E]: src = ei, dst = ei+EE
    const int*   batch = (const int*)d_in[2];
    const float* W1 = (const float*)d_in[3];
    const float* a1s = (const float*)d_in[4];
    const float* a1d = (const float*)d_in[5];
    const float* b1 = (const float*)d_in[6];
    const float* W2 = (const float*)d_in[7];
    const float* a2s = (const float*)d_in[8];
    const float* a2d = (const float*)d_in[9];
    const float* b2 = (const float*)d_in[10];
    const float* W3 = (const float*)d_in[11];
    const float* a3s = (const float*)d_in[12];
    const float* a3d = (const float*)d_in[13];
    const float* b3 = (const float*)d_in[14];
    const float* linW = (const float*)d_in[15];
    const float* linb = (const float*)d_in[16];
    float* out = (float*)d_out;

    char* ws = (char*)d_ws;
    size_t off = 0;
    auto alloc = [&](size_t bytes) -> void* {
        void* p = ws + off;
        off = (off + bytes + 255) & ~(size_t)255;
        return p;
    };
    unsigned short* hBf = (unsigned short*)alloc((size_t)NN * 64 * 2);  // bf16 projected features
    float* hF     = (float*)alloc((size_t)NN * 64 * 4);                  // fp32 layer outputs
    float* ALs    = (float*)alloc((size_t)NN * 8 * 4);
    float* ALd    = (float*)alloc((size_t)NN * 8 * 4);
    int*   rowptr = (int*)alloc((size_t)(NN + 1) * 4);
    int*   bcnt   = (int*)alloc(NB * 4);
    int*   bfill  = (int*)alloc(NB * 4);
    int*   bbase  = (int*)alloc((NB + 1) * 4);
    uint32* bpack = (uint32*)alloc((size_t)EE * 4);
    int*   col    = (int*)alloc((size_t)EE * 4);
    float* sums   = (float*)alloc((size_t)(GG * 64 + GG) * 4);
    float* gcnt   = sums + GG * 64;

    const int NBLK = (NN + 255) / 256;
    const int HB = (EE + EPH - 1) / EPH;   // 196
    const int SB = (EE + EPS - 1) / EPS;   // 391

    hipMemsetAsync(bcnt, 0, NB * 4, stream);
    hipMemsetAsync(bfill, 0, NB * 4, stream);
    bhist_kernel<<<HB, 512, 0, stream>>>(ei + EE, bcnt, EE);
    bscan_kernel<<<1, 512, 0, stream>>>(bcnt, bbase);
    bscatter_kernel<<<SB, 512, 0, stream>>>(ei, ei + EE, bfill, bbase, bpack, EE);
    bsort_kernel<<<NB, 256, 0, stream>>>(bpack, bbase, rowptr, col);

    const int GB = (NN + 63) / 64;    // 1563 blocks, 64 rows each
    const int AB = (NN + 31) / 32;    // 3125 blocks, 32 nodes each

    gemm_al_kernel<128><<<GB, 256, 0, stream>>>(x, W1, a1s, a1d, hBf, ALs, ALd, NN);
    agg_kernel<<<AB, 256, 0, stream>>>(hBf, ALs, ALd, rowptr, col, b1, hF, NN);

    gemm_al_kernel<64><<<GB, 256, 0, stream>>>(hF, W2, a2s, a2d, hBf, ALs, ALd, NN);
    agg_kernel<<<AB, 256, 0, stream>>>(hBf, ALs, ALd, rowptr, col, b2, hF, NN);

    gemm_al_kernel<64><<<GB, 256, 0, stream>>>(hF, W3, a3s, a3d, hBf, ALs, ALd, NN);
    agg_kernel<<<AB, 256, 0, stream>>>(hBf, ALs, ALd, rowptr, col, b3, hF, NN);

    hipMemsetAsync(sums, 0, (size_t)(GG * 64 + GG) * 4, stream);
    pool_kernel<<<NBLK, 256, 0, stream>>>(hF, batch, sums, gcnt, NN);
    final_kernel<<<3, 256, 0, stream>>>(sums, gcnt, linW, linb, out);
}

// Round 10
// 414.880 us; speedup vs baseline: 1.5540x; 1.0342x over previous
//
#include <hip/hip_runtime.h>
#include <math.h>

#define NN 100000
#define EE 1600000
#define GG 64
#define NCLS 10

#define BSH 8                 // bucket = dst >> 8 (256 nodes per bucket)
#define NB 391                // ceil(NN / 256)
#define EPH 8192              // edges per block in bhist
#define EPS 4096              // edges per block in bscatter
#define CAPS 5120             // bsort LDS staging capacity (ints); mean bucket = 4092

typedef unsigned int uint32;

__device__ __forceinline__ unsigned short f2bf(float f) {
    unsigned u = __float_as_uint(f);
    unsigned r = (u + 0x7fffu + ((u >> 16) & 1u)) >> 16;   // RNE
    return (unsigned short)r;
}

// ---------------- CSR build: two-level counting sort ----------------

__global__ __launch_bounds__(512) void bhist_kernel(const int* __restrict__ dst,
                                                    int* __restrict__ bcnt, int n) {
    __shared__ int h[NB];
    int tid = threadIdx.x;
    for (int i = tid; i < NB; i += 512) h[i] = 0;
    __syncthreads();
    int e0 = blockIdx.x * EPH;
    int e1 = min(e0 + EPH, n);
    for (int e = e0 + tid; e < e1; e += 512) atomicAdd(&h[dst[e] >> BSH], 1);
    __syncthreads();
    for (int i = tid; i < NB; i += 512)
        if (h[i]) atomicAdd(&bcnt[i], h[i]);
}

// exclusive scan of bucket counts, each bucket PADDED to a multiple of 4
// (so bpack/col bucket ranges are 16B-aligned; real sizes stay in bcnt)
__global__ __launch_bounds__(512) void bscan_kernel(const int* __restrict__ bcnt,
                                                    int* __restrict__ bbase) {
    int tid = threadIdx.x;
    int lane = tid & 63, wv = tid >> 6;
    int v = (tid < NB) ? ((bcnt[tid] + 3) & ~3) : 0;
    int inc = v;
#pragma unroll
    for (int off = 1; off < 64; off <<= 1) {
        int t = __shfl_up(inc, off);
        if (lane >= off) inc += t;
    }
    __shared__ int wtot[8];
    if (lane == 63) wtot[wv] = inc;
    __syncthreads();
    if (tid < 8) {
        int t = wtot[tid];
#pragma unroll
        for (int off = 1; off < 8; off <<= 1) {
            int u = __shfl_up(t, off, 8);
            if (tid >= off) t += u;
        }
        wtot[tid] = t;
    }
    __syncthreads();
    if (wv > 0) inc += wtot[wv - 1];
    if (tid < NB) bbase[tid + 1] = inc;
    if (tid == 0) bbase[0] = 0;
}

// scatter edges into bucket-ordered packed words (src<<8 | dst&255);
// LDS-staged so global writes are dense runs; wave-scan (2 barriers, not 18)
__global__ __launch_bounds__(512) void bscatter_kernel(
    const int* __restrict__ src, const int* __restrict__ dst,
    int* __restrict__ bfill, const int* __restrict__ bbase,
    uint32* __restrict__ bpack, int n) {
    __shared__ int hist[512], gbase[512], lbase[512], cnt2[512];
    __shared__ int wtot[8];
    __shared__ uint32 lsd[EPS];
    __shared__ unsigned short bkt[EPS];
    int tid = threadIdx.x;
    int lane = tid & 63, wv = tid >> 6;
    int e0 = blockIdx.x * EPS;
    int e1 = min(e0 + EPS, n);

    hist[tid] = 0;
    cnt2[tid] = 0;
    __syncthreads();
    for (int e = e0 + tid; e < e1; e += 512) atomicAdd(&hist[dst[e] >> BSH], 1);
    __syncthreads();
    int h = hist[tid];
    int inc = h;
#pragma unroll
    for (int off = 1; off < 64; off <<= 1) {
        int t = __shfl_up(inc, off);
        if (lane >= off) inc += t;
    }
    if (lane == 63) wtot[wv] = inc;
    __syncthreads();
    if (tid < 8) {
        int t = wtot[tid];
#pragma unroll
        for (int off = 1; off < 8; off <<= 1) {
            int u = __shfl_up(t, off, 8);
            if (tid >= off) t += u;
        }
        wtot[tid] = t;
    }
    __syncthreads();
    if (wv > 0) inc += wtot[wv - 1];
    int lb = inc - h;
    lbase[tid] = lb;
    int go = h > 0 ? atomicAdd(&bfill[tid], h) : 0;
    gbase[tid] = ((tid < NB) ? bbase[tid] : 0) + go - lb;  // g = gbase[b] + slot
    __syncthreads();
    for (int e = e0 + tid; e < e1; e += 512) {
        int s = src[e], dd = dst[e];
        int b = dd >> BSH;
        int r = atomicAdd(&cnt2[b], 1);
        int slot = lbase[b] + r;
        lsd[slot] = ((uint32)s << 8) | (uint32)(dd & 255);
        bkt[slot] = (unsigned short)b;
    }
    __syncthreads();
    int m = e1 - e0;
    for (int i = tid; i < m; i += 512)
        bpack[gbase[bkt[i]] + i] = lsd[i];
}

// per-bucket counting sort -> rp/re + col; uint4-vectorized (bucket base 16B-aligned)
__global__ __launch_bounds__(256) void bsort_kernel(
    const uint32* __restrict__ bpack, const int* __restrict__ bbase,
    const int* __restrict__ bcnt,
    int* __restrict__ rp, int* __restrict__ re, int* __restrict__ col) {
    __shared__ int cnt[256], cnt2[256];
    __shared__ int wtot[4];
    __shared__ int stage[CAPS];
    int b = blockIdx.x;
    int tid = threadIdx.x;
    int lane = tid & 63, wv = tid >> 6;
    int ebeg = bbase[b];
    int sz = bcnt[b];                 // real edge count (pad slots never touched)
    int n0 = b << BSH;
    int nn = min(256, NN - n0);

    cnt[tid] = 0;
    cnt2[tid] = 0;
    __syncthreads();
    // count (4 edges / iteration)
    const uint4* bq = (const uint4*)(bpack + ebeg);
    int nq = sz >> 2;
    for (int i = tid; i < nq; i += 256) {
        uint4 p = bq[i];
        atomicAdd(&cnt[p.x & 255u], 1);
        atomicAdd(&cnt[p.y & 255u], 1);
        atomicAdd(&cnt[p.z & 255u], 1);
        atomicAdd(&cnt[p.w & 255u], 1);
    }
    for (int e = (nq << 2) + tid; e < sz; e += 256)
        atomicAdd(&cnt[bpack[ebeg + e] & 255u], 1);
    __syncthreads();
    // inclusive wave-scan of cnt
    int c = cnt[tid];
    int inc = c;
#pragma unroll
    for (int off = 1; off < 64; off <<= 1) {
        int t = __shfl_up(inc, off);
        if (lane >= off) inc += t;
    }
    if (lane == 63) wtot[wv] = inc;
    __syncthreads();
    if (tid < 4) {
        int t = wtot[tid];
#pragma unroll
        for (int off = 1; off < 4; off <<= 1) {
            int u = __shfl_up(t, off, 4);
            if (tid >= off) t += u;
        }
        wtot[tid] = t;
    }
    __syncthreads();
    if (wv > 0) inc += wtot[wv - 1];
    int excl = inc - c;
    cnt[tid] = excl;  // reuse cnt as exclusive offsets
    if (tid < nn) {
        rp[n0 + tid] = ebeg + excl;
        re[n0 + tid] = ebeg + inc;
    }
    __syncthreads();
    bool fits = sz <= CAPS;
    // rank + stage (4 edges / iteration)
    for (int i = tid; i < nq; i += 256) {
        uint4 p = bq[i];
        int d0 = (int)(p.x & 255u), d1 = (int)(p.y & 255u);
        int d2 = (int)(p.z & 255u), d3 = (int)(p.w & 255u);
        int p0 = cnt[d0] + atomicAdd(&cnt2[d0], 1);
        int p1 = cnt[d1] + atomicAdd(&cnt2[d1], 1);
        int p2 = cnt[d2] + atomicAdd(&cnt2[d2], 1);
        int p3 = cnt[d3] + atomicAdd(&cnt2[d3], 1);
        if (fits) {
            stage[p0] = (int)(p.x >> 8); stage[p1] = (int)(p.y >> 8);
            stage[p2] = (int)(p.z >> 8); stage[p3] = (int)(p.w >> 8);
        } else {
            col[ebeg + p0] = (int)(p.x >> 8); col[ebeg + p1] = (int)(p.y >> 8);
            col[ebeg + p2] = (int)(p.z >> 8); col[ebeg + p3] = (int)(p.w >> 8);
        }
    }
    for (int e = (nq << 2) + tid; e < sz; e += 256) {
        uint32 p = bpack[ebeg + e];
        int dl = (int)(p & 255u);
        int pos = cnt[dl] + atomicAdd(&cnt2[dl], 1);
        if (fits) stage[pos] = (int)(p >> 8);
        else col[ebeg + pos] = (int)(p >> 8);
    }
    __syncthreads();
    if (fits) {
        uint4* colq = (uint4*)(col + ebeg);
        const uint4* stq = (const uint4*)stage;
        for (int i = tid; i < nq; i += 256) colq[i] = stq[i];
        for (int i = (nq << 2) + tid; i < sz; i += 256) col[ebeg + i] = stage[i];
    }
}

// ---------------- GEMM h = X @ W (+ attention logits), bf16 H output ----------------
// Register-tiled: block = 64 rows x 64 cols, thread (rg=t>>4, cg=t&15) owns a
// 4x4 tile. Xs rows padded +4 floats: row stride 528B -> rg groups 16 banks
// apart (2-way aliasing only, free) instead of 4-way same-bank conflicts.

template <int K>
__global__ __launch_bounds__(256) void gemm_al_kernel(
    const float* __restrict__ X, const float* __restrict__ W,
    const float* __restrict__ a_src, const float* __restrict__ a_dst,
    unsigned short* __restrict__ H, float* __restrict__ ALs, float* __restrict__ ALd,
    int nrows) {
    const int KP = K + 4;
    __shared__ float Xs[64 * (K + 4)];
    __shared__ float Ws[K * 64];
    int tid = threadIdx.x;
    int r0 = blockIdx.x * 64;

    {
        const float4* Wg = (const float4*)W;
        float4* Ws4 = (float4*)Ws;
        for (int i = tid; i < K * 16; i += 256) Ws4[i] = Wg[i];
    }
    {
        const float4* Xg = (const float4*)(X + (size_t)r0 * K);
        const int nq = 64 * K / 4;
        int valid_q = (min(64, nrows - r0) * K) / 4;
        const int QPR = K / 4;  // quads per row
        for (int i = tid; i < nq; i += 256) {
            int row = i / QPR, wq = i % QPR;
            float4 v = (i < valid_q) ? Xg[i] : make_float4(0.f, 0.f, 0.f, 0.f);
            *(float4*)&Xs[row * KP + wq * 4] = v;
        }
    }
    __syncthreads();

    int cg = tid & 15, rg = tid >> 4;
    int rbase = rg * 4;
    float4 acc0 = make_float4(0.f, 0.f, 0.f, 0.f);
    float4 acc1 = acc0, acc2 = acc0, acc3 = acc0;

#pragma unroll 2
    for (int k = 0; k < K; k += 4) {
        float4 x0 = *(const float4*)&Xs[(rbase + 0) * KP + k];
        float4 x1 = *(const float4*)&Xs[(rbase + 1) * KP + k];
        float4 x2 = *(const float4*)&Xs[(rbase + 2) * KP + k];
        float4 x3 = *(const float4*)&Xs[(rbase + 3) * KP + k];
        float4 w0 = *(const float4*)&Ws[(k + 0) * 64 + 4 * cg];
        float4 w1 = *(const float4*)&Ws[(k + 1) * 64 + 4 * cg];
        float4 w2 = *(const float4*)&Ws[(k + 2) * 64 + 4 * cg];
        float4 w3 = *(const float4*)&Ws[(k + 3) * 64 + 4 * cg];
#define FMA4(A, S, WV) \
        A.x = fmaf(S, WV.x, A.x); A.y = fmaf(S, WV.y, A.y); \
        A.z = fmaf(S, WV.z, A.z); A.w = fmaf(S, WV.w, A.w)
        FMA4(acc0, x0.x, w0); FMA4(acc1, x1.x, w0); FMA4(acc2, x2.x, w0); FMA4(acc3, x3.x, w0);
        FMA4(acc0, x0.y, w1); FMA4(acc1, x1.y, w1); FMA4(acc2, x2.y, w1); FMA4(acc3, x3.y, w1);
        FMA4(acc0, x0.z, w2); FMA4(acc1, x1.z, w2); FMA4(acc2, x2.z, w2); FMA4(acc3, x3.z, w2);
        FMA4(acc0, x0.w, w3); FMA4(acc1, x1.w, w3); FMA4(acc2, x2.w, w3); FMA4(acc3, x3.w, w3);
#undef FMA4
    }

    int hh = cg >> 1;
    float4 as4 = ((const float4*)a_src)[cg];
    float4 ad4 = ((const float4*)a_dst)[cg];
    float4 accs[4] = {acc0, acc1, acc2, acc3};
#pragma unroll
    for (int i = 0; i < 4; ++i) {
        int r = r0 + rbase + i;
        if (r < nrows) {
            ushort4 p;
            p.x = f2bf(accs[i].x); p.y = f2bf(accs[i].y);
            p.z = f2bf(accs[i].z); p.w = f2bf(accs[i].w);
            ((ushort4*)H)[(size_t)r * 16 + cg] = p;   // row = 64 bf16 = 16 ushort4
            float ps = accs[i].x * as4.x + accs[i].y * as4.y +
                       accs[i].z * as4.z + accs[i].w * as4.w;
            float pd = accs[i].x * ad4.x + accs[i].y * ad4.y +
                       accs[i].z * ad4.z + accs[i].w * ad4.w;
            ps += __shfl_xor(ps, 1);
            pd += __shfl_xor(pd, 1);
            if ((cg & 1) == 0) {
                ALs[r * 8 + hh] = ps;
                ALd[r * 8 + hh] = pd;
            }
        }
    }
}

// ---------------- GAT aggregation: lane-per-(node,head), bf16 H gather ----------------
// Wave = 8 nodes x 8 heads. Lane (slot,head) owns features head*8..head*8+7 of node
// slot and serially walks its node's edge list [rp[d], re[d]). Unrolled x4.

__global__ __launch_bounds__(256, 6) void agg_kernel(
    const unsigned short* __restrict__ H, const float* __restrict__ ALs,
    const float* __restrict__ ALd, const int* __restrict__ rp,
    const int* __restrict__ re, const int* __restrict__ col,
    const float* __restrict__ bias, float* __restrict__ Out, int n) {
    int tid = threadIdx.x;
    int lane = tid & 63;
    int slot = lane >> 3, head = lane & 7;
    int wid = blockIdx.x * 4 + (tid >> 6);
    int d = wid * 8 + slot;
    bool active = d < n;
    if (!active) d = n - 1;
    const uint4* __restrict__ Hq = (const uint4*)H;   // row = 8 uint4

    float ad = ALd[d * 8 + head];
    float acc0 = 0.f, acc1 = 0.f, acc2 = 0.f, acc3 = 0.f;
    float acc4 = 0.f, acc5 = 0.f, acc6 = 0.f, acc7 = 0.f;
    float wsum = 0.f;

#define FMA8(U, W) { \
    acc0 = fmaf(W, __uint_as_float((U).x << 16), acc0); \
    acc1 = fmaf(W, __uint_as_float((U).x & 0xffff0000u), acc1); \
    acc2 = fmaf(W, __uint_as_float((U).y << 16), acc2); \
    acc3 = fmaf(W, __uint_as_float((U).y & 0xffff0000u), acc3); \
    acc4 = fmaf(W, __uint_as_float((U).z << 16), acc4); \
    acc5 = fmaf(W, __uint_as_float((U).z & 0xffff0000u), acc5); \
    acc6 = fmaf(W, __uint_as_float((U).w << 16), acc6); \
    acc7 = fmaf(W, __uint_as_float((U).w & 0xffff0000u), acc7); }

    {   // self loop
        uint4 u = Hq[(size_t)d * 8 + head];
        float e = ALs[d * 8 + head] + ad;
        e = fmaxf(e, 0.2f * e);
        float w = __expf(e);
        FMA8(u, w);
        wsum = w;
    }

    int k = rp[d], kend = re[d];
    for (; k + 4 <= kend; k += 4) {
        int s0 = col[k], s1 = col[k + 1], s2 = col[k + 2], s3 = col[k + 3];
        uint4 u0 = Hq[(size_t)s0 * 8 + head];
        uint4 u1 = Hq[(size_t)s1 * 8 + head];
        uint4 u2 = Hq[(size_t)s2 * 8 + head];
        uint4 u3 = Hq[(size_t)s3 * 8 + head];
        float a0 = ALs[s0 * 8 + head];
        float a1 = ALs[s1 * 8 + head];
        float a2 = ALs[s2 * 8 + head];
        float a3 = ALs[s3 * 8 + head];
        float e0 = a0 + ad; e0 = fmaxf(e0, 0.2f * e0); float w0 = __expf(e0);
        float e1 = a1 + ad; e1 = fmaxf(e1, 0.2f * e1); float w1 = __expf(e1);
        float e2 = a2 + ad; e2 = fmaxf(e2, 0.2f * e2); float w2 = __expf(e2);
        float e3 = a3 + ad; e3 = fmaxf(e3, 0.2f * e3); float w3 = __expf(e3);
        FMA8(u0, w0);
        FMA8(u1, w1);
        FMA8(u2, w2);
        FMA8(u3, w3);
        wsum += (w0 + w1) + (w2 + w3);
    }
    if (k + 2 <= kend) {
        int s0 = col[k], s1 = col[k + 1];
        uint4 u0 = Hq[(size_t)s0 * 8 + head];
        uint4 u1 = Hq[(size_t)s1 * 8 + head];
        float a0 = ALs[s0 * 8 + head];
        float a1 = ALs[s1 * 8 + head];
        float e0 = a0 + ad; e0 = fmaxf(e0, 0.2f * e0); float w0 = __expf(e0);
        float e1 = a1 + ad; e1 = fmaxf(e1, 0.2f * e1); float w1 = __expf(e1);
        FMA8(u0, w0);
        FMA8(u1, w1);
        wsum += w0 + w1;
        k += 2;
    }
    if (k < kend) {
        int s = col[k];
        uint4 u = Hq[(size_t)s * 8 + head];
        float a = ALs[s * 8 + head];
        float e = a + ad; e = fmaxf(e, 0.2f * e);
        float w = __expf(e);
        FMA8(u, w);
        wsum += w;
    }
#undef FMA8

    if (active) {
        float inv = 1.f / wsum;
        float4 b0 = ((const float4*)bias)[head * 2];
        float4 b1 = ((const float4*)bias)[head * 2 + 1];
        float4 o0, o1;
        o0.x = fmaf(acc0, inv, b0.x); o0.x = o0.x > 0.f ? o0.x : expm1f(o0.x);
        o0.y = fmaf(acc1, inv, b0.y); o0.y = o0.y > 0.f ? o0.y : expm1f(o0.y);
        o0.z = fmaf(acc2, inv, b0.z); o0.z = o0.z > 0.f ? o0.z : expm1f(o0.z);
        o0.w = fmaf(acc3, inv, b0.w); o0.w = o0.w > 0.f ? o0.w : expm1f(o0.w);
        o1.x = fmaf(acc4, inv, b1.x); o1.x = o1.x > 0.f ? o1.x : expm1f(o1.x);
        o1.y = fmaf(acc5, inv, b1.y); o1.y = o1.y > 0.f ? o1.y : expm1f(o1.y);
        o1.z = fmaf(acc6, inv, b1.z); o1.z = o1.z > 0.f ? o1.z : expm1f(o1.z);
        o1.w = fmaf(acc7, inv, b1.w); o1.w = o1.w > 0.f ? o1.w : expm1f(o1.w);
        ((float4*)Out)[(size_t)d * 16 + head * 2] = o0;
        ((float4*)Out)[(size_t)d * 16 + head * 2 + 1] = o1;
    }
}

// ---------------- global mean pool (batch is sorted) ----------------

__global__ void pool_kernel(const float* __restrict__ H, const int* __restrict__ batch,
                            float* __restrict__ sums, float* __restrict__ cnt, int n) {
    int gw = (int)((blockIdx.x * blockDim.x + threadIdx.x) >> 6);
    int lane = threadIdx.x & 63;
    int n0 = gw * 64;
    if (n0 >= n) return;
    int n1 = min(n0 + 64, n);
    int curb = batch[n0];
    float local = 0.f, c_local = 0.f;
    for (int i = n0; i < n1; ++i) {
        int b = batch[i];
        if (b != curb) {
            atomicAdd(&sums[curb * 64 + lane], local);
            if (lane == 0) atomicAdd(&cnt[curb], c_local);
            local = 0.f;
            c_local = 0.f;
            curb = b;
        }
        local += H[(size_t)i * 64 + lane];
        c_local += 1.f;
    }
    atomicAdd(&sums[curb * 64 + lane], local);
    if (lane == 0) atomicAdd(&cnt[curb], c_local);
}

__global__ void final_kernel(const float* __restrict__ sums, const float* __restrict__ cnt,
                             const float* __restrict__ W, const float* __restrict__ b,
                             float* __restrict__ out) {
    int t = blockIdx.x * blockDim.x + threadIdx.x;
    if (t >= GG * NCLS) return;
    int g = t / NCLS, k = t % NCLS;
    float c = cnt[g];
    if (c < 1.f) c = 1.f;
    float inv = 1.f / c;
    float acc = b[k];
#pragma unroll
    for (int cc = 0; cc < 64; ++cc)
        acc = fmaf(sums[g * 64 + cc] * inv, W[cc * NCLS + k], acc);
    out[t] = acc;
}

// ---------------- launch ----------------

extern "C" void kernel_launch(void* const* d_in, const int* in_sizes, int n_in,
                              void* d_out, int out_size, void* d_ws, size_t ws_size,
                              hipStream_t stream) {
    const float* x    = (const float*)d_in[0];
    const int*   ei   = (const int*)d_in[1];   // [2,E]: src = ei, dst = ei+EE
    const int*   batch = (const int*)d_in[2];
    const float* W1 = (const float*)d_in[3];
    const float* a1s = (const float*)d_in[4];
    const float* a1d = (const float*)d_in[5];
    const float* b1 = (const float*)d_in[6];
    const float* W2 = (const float*)d_in[7];
    const float* a2s = (const float*)d_in[8];
    const float* a2d = (const float*)d_in[9];
    const float* b2 = (const float*)d_in[10];
    const float* W3 = (const float*)d_in[11];
    const float* a3s = (const float*)d_in[12];
    const float* a3d = (const float*)d_in[13];
    const float* b3 = (const float*)d_in[14];
    const float* linW = (const float*)d_in[15];
    const float* linb = (const float*)d_in[16];
    float* out = (float*)d_out;

    char* ws = (char*)d_ws;
    size_t off = 0;
    auto alloc = [&](size_t bytes) -> void* {
        void* p = ws + off;
        off = (off + bytes + 255) & ~(size_t)255;
        return p;
    };
    unsigned short* hBf = (unsigned short*)alloc((size_t)NN * 64 * 2);  // bf16 projected features
    float* hF     = (float*)alloc((size_t)NN * 64 * 4);                  // fp32 layer outputs
    float* ALs    = (float*)alloc((size_t)NN * 8 * 4);
    float* ALd    = (float*)alloc((size_t)NN * 8 * 4);
    int*   rp     = (int*)alloc((size_t)NN * 4);
    int*   reArr  = (int*)alloc((size_t)NN * 4);
    int*   bcnt   = (int*)alloc((size_t)2 * NB * 4);   // bcnt + bfill contiguous
    int*   bfill  = bcnt + NB;
    int*   bbase  = (int*)alloc((NB + 1) * 4);
    uint32* bpack = (uint32*)alloc(((size_t)EE + 4 * NB) * 4);
    int*   col    = (int*)alloc(((size_t)EE + 4 * NB) * 4);
    float* sums   = (float*)alloc((size_t)(GG * 64 + GG) * 4);
    float* gcnt   = sums + GG * 64;

    const int NBLK = (NN + 255) / 256;
    const int HB = (EE + EPH - 1) / EPH;   // 196
    const int SB = (EE + EPS - 1) / EPS;   // 391

    hipMemsetAsync(bcnt, 0, (size_t)2 * NB * 4, stream);
    bhist_kernel<<<HB, 512, 0, stream>>>(ei + EE, bcnt, EE);
    bscan_kernel<<<1, 512, 0, stream>>>(bcnt, bbase);
    bscatter_kernel<<<SB, 512, 0, stream>>>(ei, ei + EE, bfill, bbase, bpack, EE);
    bsort_kernel<<<NB, 256, 0, stream>>>(bpack, bbase, bcnt, rp, reArr, col);

    const int GB = (NN + 63) / 64;    // 1563 blocks, 64 rows each
    const int AB = (NN + 31) / 32;    // 3125 blocks, 32 nodes each

    gemm_al_kernel<128><<<GB, 256, 0, stream>>>(x, W1, a1s, a1d, hBf, ALs, ALd, NN);
    agg_kernel<<<AB, 256, 0, stream>>>(hBf, ALs, ALd, rp, reArr, col, b1, hF, NN);

    gemm_al_kernel<64><<<GB, 256, 0, stream>>>(hF, W2, a2s, a2d, hBf, ALs, ALd, NN);
    agg_kernel<<<AB, 256, 0, stream>>>(hBf, ALs, ALd, rp, reArr, col, b2, hF, NN);

    gemm_al_kernel<64><<<GB, 256, 0, stream>>>(hF, W3, a3s, a3d, hBf, ALs, ALd, NN);
    agg_kernel<<<AB, 256, 0, stream>>>(hBf, ALs, ALd, rp, reArr, col, b3, hF, NN);

    hipMemsetAsync(sums, 0, (size_t)(GG * 64 + GG) * 4, stream);
    pool_kernel<<<NBLK, 256, 0, stream>>>(hF, batch, sums, gcnt, NN);
    final_kernel<<<3, 256, 0, stream>>>(sums, gcnt, linW, linb, out);
}